// Round 13
// baseline (639.207 us; speedup 1.0000x reference)
//
#include <hip/hip_runtime.h>
#include <hip/hip_bf16.h>
#include <cstdint>

#define C_NU 100000
#define C_NI 100000
#define C_DIM 64
#define C_Q 5
#define C_NE 2000000
#define C_B 4096
#define C_P 10
#define NROW 100000
#define NCB 196      // coarse buckets of 512 rows
#define NCHK 256     // chunks in pass A
#define CHUNK 7813   // ceil(2M/256)

typedef unsigned short u16;
typedef unsigned char u8;
typedef __attribute__((ext_vector_type(8))) short short8;
typedef __attribute__((ext_vector_type(4))) float f32x4;

__device__ static inline int rfl(int v) { return __builtin_amdgcn_readfirstlane(v); }
__device__ static inline uint32_t rflu(uint32_t v) {
  return (uint32_t)__builtin_amdgcn_readfirstlane((int)v);
}

// single-instruction exp2 (exp2f lowers to a slow OCML sequence without fast-math)
__device__ static inline float fast_exp2(float x) {
  float r;
  asm("v_exp_f32 %0, %1" : "=v"(r) : "v"(x));
  return r;
}

// ---------------- Threefry-2x32 (JAX-compatible), 20 rounds ----------------
__host__ __device__ static inline void tf2x32(uint32_t k0, uint32_t k1,
                                              uint32_t& x0, uint32_t& x1) {
  uint32_t k2 = k0 ^ k1 ^ 0x1BD11BDAu;
#define TFR(r) { x0 += x1; x1 = (x1 << r) | (x1 >> (32 - r)); x1 ^= x0; }
  x0 += k0; x1 += k1;
  TFR(13) TFR(15) TFR(26) TFR(6)
  x0 += k1; x1 += k2 + 1u;
  TFR(17) TFR(29) TFR(16) TFR(24)
  x0 += k2; x1 += k0 + 2u;
  TFR(13) TFR(15) TFR(26) TFR(6)
  x0 += k0; x1 += k1 + 3u;
  TFR(17) TFR(29) TFR(16) TFR(24)
  x0 += k1; x1 += k2 + 4u;
  TFR(13) TFR(15) TFR(26) TFR(6)
  x0 += k2; x1 += k0 + 5u;
#undef TFR
}

// partitionable-mode random bits at flat index idx (hi counter = 0)
__device__ static inline float tf_uniform(uint32_t k0, uint32_t k1, uint32_t idx) {
  uint32_t x0 = 0u, x1 = idx;
  tf2x32(k0, k1, x0, x1);
  uint32_t bits = x0 ^ x1;
  return __uint_as_float((bits >> 9) | 0x3F800000u) - 1.0f;
}

__device__ static inline float leaky(float x) { return x >= 0.f ? x : 0.5f * x; }

__device__ static inline u16 f2bf(float f) {  // RNE fp32->bf16
  uint32_t x = __float_as_uint(f);
  return (u16)((x + 0x7FFFu + ((x >> 16) & 1u)) >> 16);
}
__device__ static inline float bf2f(u16 u) {
  return __uint_as_float((uint32_t)u << 16);
}

// fp8 store: byte = sign | 7-bit (4-exp,3-mant) of (x*256), RNE, underflow->0.
__device__ static inline u8 f2fp8(float x) {
  float t = x * 256.f;
  uint32_t sgn = (__float_as_uint(t) >> 24) & 0x80u;
  float a = fabsf(t) * 0x1p-120f;
  uint32_t u = __float_as_uint(a);
  u += 0x7FFFFu + ((u >> 20) & 1u);
  uint32_t mag = u >> 20;
  if (mag > 0x7Fu) mag = 0x7Fu;
  return (u8)(sgn | mag);
}
__device__ static inline float fp8dec(uint32_t b) {  // * 2^-112 folded into weight
  return __uint_as_float(((b & 0x80u) << 24) | ((b & 0x7Fu) << 20));
}

// ---------------- constant maps for the 16 info_nce calls ----------------
// normbuf slots: 0:Zu1 1:Zu2 2:Zi1 3:Zi2 4:Zdu1 5:Zdu2 6:Zdi1 7:Zdi2 8:Gu1 9:Gu2 10:Gi1 11:Gi2
__constant__ int c_gsel[16] = {0,1,2,3, 0,2, 4,5,6,7, 4,6, 0,1,2,3};
__constant__ int c_hsrc[16] = {8,9,10,11, 1,3, 8,9,10,11, 5,7, 4,5,6,7};
// W order: 0:ng0 1:ng1 2:nn 3:dg0 4:dg1 5:dd 6:nd0 7:nd1
__constant__ int c_wsel[16] = {0,1,0,1, 2,2, 3,4,3,4, 5,5, 6,7,6,7};
// slots: 0:n 1:d 2:nn 3:dd 4:nd (5: loss_r sum)
__constant__ int c_slot[16] = {0,0,0,0, 2,2, 1,1,1,1, 3,3, 4,4,4,4};

struct WPtrs { const float* W[8]; };
struct NceKeys { uint32_t k0[16]; uint32_t k1[16]; };
struct DropKeys { uint32_t a[8]; };

// ---------------- two-level counting sort ----------------

__global__ __launch_bounds__(256) void passA_hist(
    const int* __restrict__ rows, const int* __restrict__ cols,
    uint32_t* __restrict__ cntA) {
  __shared__ uint32_t h[NCB];
  const int dir = blockIdx.y, c = blockIdx.x, t = threadIdx.x;
  for (int i = t; i < NCB; i += 256) h[i] = 0u;
  __syncthreads();
  const int e0 = c * CHUNK, e1 = min(e0 + CHUNK, C_NE);
  const int* ids = dir ? cols : rows;
  for (int e = e0 + t; e < e1; e += 256) atomicAdd(&h[ids[e] >> 9], 1u);
  __syncthreads();
  for (int i = t; i < NCB; i += 256) cntA[(dir * NCB + i) * NCHK + c] = h[i];
}

__global__ __launch_bounds__(512) void scanA1(
    const uint32_t* __restrict__ cntA, uint32_t* __restrict__ offs,
    uint32_t* __restrict__ bsum) {
  __shared__ uint32_t s[512];
  const int b = blockIdx.x, t = threadIdx.x;
  const int idx = b * 512 + t;
  uint32_t v = cntA[idx];
  s[t] = v;
  __syncthreads();
  for (int off = 1; off < 512; off <<= 1) {
    uint32_t a = (t >= off) ? s[t - off] : 0u;
    __syncthreads();
    s[t] += a;
    __syncthreads();
  }
  offs[idx] = s[t] - v;
  if (t == 511) bsum[b] = s[511];
}

__global__ __launch_bounds__(256) void scanA2(
    const uint32_t* __restrict__ bsum, uint32_t* __restrict__ boff) {
  __shared__ uint32_t s[256];
  const int t = threadIdx.x;
  uint32_t v = (t < NCB) ? bsum[t] : 0u;
  s[t] = v;
  __syncthreads();
  for (int off = 1; off < 256; off <<= 1) {
    uint32_t a = (t >= off) ? s[t - off] : 0u;
    __syncthreads();
    s[t] += a;
    __syncthreads();
  }
  if (t < NCB) boff[t] = s[t] - v;
}

__global__ __launch_bounds__(512) void scanA3(
    uint32_t* __restrict__ offs, const uint32_t* __restrict__ boff) {
  offs[blockIdx.x * 512 + threadIdx.x] += boff[blockIdx.x];
}

// record.x = src(17b) | keepL0<<17 | keepL1<<18 | (dst&511)<<19
__global__ __launch_bounds__(256) void passA_scatter(
    const int* __restrict__ rows, const int* __restrict__ cols,
    const float* __restrict__ vals, const uint32_t* __restrict__ offs,
    uint2* __restrict__ edgesA, DropKeys dk) {
  __shared__ uint32_t lofs[NCB];
  const int dir = blockIdx.y, c = blockIdx.x, t = threadIdx.x;
  for (int i = t; i < NCB; i += 256) lofs[i] = offs[(dir * NCB + i) * NCHK + c];
  __syncthreads();
  const int e0 = c * CHUNK, e1 = min(e0 + CHUNK, C_NE);
  const uint32_t kA0 = dk.a[dir * 4 + 0], kA1 = dk.a[dir * 4 + 1];
  const uint32_t kB0 = dk.a[dir * 4 + 2], kB1 = dk.a[dir * 4 + 3];
  for (int e = e0 + t; e < e1; e += 256) {
    const int r = rows[e], cc = cols[e];
    const int dst = dir ? cc : r, src = dir ? r : cc;
    const uint32_t kl0 = (tf_uniform(kA0, kA1, (uint32_t)e) < 0.9f) ? 1u : 0u;
    const uint32_t kl1 = (tf_uniform(kB0, kB1, (uint32_t)e) < 0.9f) ? 1u : 0u;
    const uint32_t x = (uint32_t)src | (kl0 << 17) | (kl1 << 18) |
                       ((uint32_t)(dst & 511) << 19);
    const uint32_t pos = atomicAdd(&lofs[dst >> 9], 1u);
    edgesA[pos] = make_uint2(x, __float_as_uint(vals[e]));
  }
}

__global__ __launch_bounds__(512) void passB_kernel(
    const uint2* __restrict__ edgesA, const uint32_t* __restrict__ offs,
    uint2* __restrict__ edgesB, uint32_t* __restrict__ starts) {
  __shared__ uint32_t cnt[512];
  __shared__ uint32_t scn[512];
  const int dir = blockIdx.y, cb = blockIdx.x, t = threadIdx.x;
  const uint32_t segStart = offs[(dir * NCB + cb) * NCHK];
  const uint32_t segEnd = (dir == 1 && cb == NCB - 1)
                              ? (uint32_t)(2 * C_NE)
                              : offs[(dir * NCB + cb + 1) * NCHK];
  cnt[t] = 0u;
  __syncthreads();
  for (uint32_t e = segStart + t; e < segEnd; e += 512)
    atomicAdd(&cnt[(edgesA[e].x >> 19) & 511u], 1u);
  __syncthreads();
  uint32_t v = cnt[t];
  scn[t] = v;
  __syncthreads();
  for (int off = 1; off < 512; off <<= 1) {
    uint32_t a = (t >= off) ? scn[t - off] : 0u;
    __syncthreads();
    scn[t] += a;
    __syncthreads();
  }
  const uint32_t rstart = segStart + scn[t] - v;
  const int grow = cb * 512 + t;
  if (grow < NROW) starts[dir * (NROW + 1) + grow] = rstart;
  if (cb == NCB - 1 && t == 0) starts[dir * (NROW + 1) + NROW] = segEnd;
  cnt[t] = rstart;
  __syncthreads();
  for (uint32_t e = segStart + t; e < segEnd; e += 512) {
    const uint2 q = edgesA[e];
    const uint32_t pos = atomicAdd(&cnt[(q.x >> 19) & 511u], 1u);
    edgesB[pos] = q;
  }
}

// ---------------- fp32 -> fp8 table convert ----------------
__global__ __launch_bounds__(256) void fp8_convert(
    const float* __restrict__ src, u8* __restrict__ dst, int n4) {
  int i = blockIdx.x * 256 + threadIdx.x;
  if (i >= n4) return;
  float4 v = ((const float4*)src)[i];
  uint32_t o = (uint32_t)f2fp8(v.x) | ((uint32_t)f2fp8(v.y) << 8) |
               ((uint32_t)f2fp8(v.z) << 16) | ((uint32_t)f2fp8(v.w) << 24);
  ((uint32_t*)dst)[i] = o;
}

// Wt16[w][d][k] = bf16(W[w][k][d])  (pre-transposed for MFMA B-operand)
__global__ __launch_bounds__(256) void w16_prep(WPtrs wp, u16* __restrict__ Wt16) {
  int i = blockIdx.x * 256 + threadIdx.x;
  if (i >= 8 * 4096) return;
  int w = i >> 12, kd = i & 4095, k = kd >> 6, d = kd & 63;
  Wt16[w * 4096 + d * 64 + k] = f2bf(wp.W[w][k * 64 + d]);
}

// ---------------- fused spmm (wave/row, scalarized, fp8 gathers, one dir) -------
__global__ __launch_bounds__(256) void spmm_row(
    const uint2* __restrict__ edges, const uint32_t* __restrict__ starts,
    const u8* __restrict__ Einf, const float* __restrict__ Eprev,
    float* __restrict__ Enext, u8* __restrict__ Enf8,
    u16* __restrict__ Zout, u16* __restrict__ Zdout,
    uint32_t nk0, uint32_t nk1, int layer) {
  const int row = rfl(blockIdx.x * 4 + (threadIdx.x >> 6));
  const int lane = threadIdx.x & 63;
  if (row >= NROW) return;
  const uint32_t s0 = rflu(starts[row]);
  const uint32_t s1 = rflu(starts[row + 1]);
  const uint32_t kbit = 1u << (17 + layer);
  const float VS = 0x1p112f;  // fp8 decode scale (2^120) * table scale (2^-8)
  float z = 0.f, zd = 0.f;
  uint32_t e = s0;
  for (; e + 4 <= s1; e += 4) {
    const uint32_t p0 = rflu(edges[e].x),     w0 = rflu(edges[e].y);
    const uint32_t p1 = rflu(edges[e + 1].x), w1 = rflu(edges[e + 1].y);
    const uint32_t p2 = rflu(edges[e + 2].x), w2 = rflu(edges[e + 2].y);
    const uint32_t p3 = rflu(edges[e + 3].x), w3 = rflu(edges[e + 3].y);
    const uint32_t b0 = Einf[(size_t)(p0 & 0x1FFFFu) * 64 + lane];
    const uint32_t b1 = Einf[(size_t)(p1 & 0x1FFFFu) * 64 + lane];
    const uint32_t b2 = Einf[(size_t)(p2 & 0x1FFFFu) * 64 + lane];
    const uint32_t b3 = Einf[(size_t)(p3 & 0x1FFFFu) * 64 + lane];
    const float x0 = fp8dec(b0), x1 = fp8dec(b1);
    const float x2 = fp8dec(b2), x3 = fp8dec(b3);
    const float v0 = __uint_as_float(w0) * VS, v1 = __uint_as_float(w1) * VS;
    const float v2 = __uint_as_float(w2) * VS, v3 = __uint_as_float(w3) * VS;
    const float d0 = (p0 & kbit) ? v0 : 0.f;
    const float d1 = (p1 & kbit) ? v1 : 0.f;
    const float d2 = (p2 & kbit) ? v2 : 0.f;
    const float d3 = (p3 & kbit) ? v3 : 0.f;
    z += v0 * x0; zd += d0 * x0;
    z += v1 * x1; zd += d1 * x1;
    z += v2 * x2; zd += d2 * x2;
    z += v3 * x3; zd += d3 * x3;
  }
  for (; e < s1; ++e) {
    const uint32_t p = rflu(edges[e].x), wv = rflu(edges[e].y);
    const float x = fp8dec(Einf[(size_t)(p & 0x1FFFFu) * 64 + lane]);
    const float v = __uint_as_float(wv) * VS;
    z += v * x;
    zd += ((p & kbit) ? v : 0.f) * x;
  }
  z = leaky(z);
  zd = leaky(zd * (1.0f / 0.9f));
  // noise-augmented view
  const float u = tf_uniform(nk0, nk1, (uint32_t)row * 64u + (uint32_t)lane);
  float ss = u * u;
#pragma unroll
  for (int off = 1; off < 64; off <<= 1) ss += __shfl_xor(ss, off);
  const float nrm = fmaxf(sqrtf(ss), 1e-12f);
  const float sg = (z > 0.f) ? 1.f : (z < 0.f ? -1.f : 0.f);
  z += sg * (u / nrm) * 0.1f;
  const size_t j = (size_t)row * 64 + lane;
  Zout[j] = f2bf(z);
  Zdout[j] = f2bf(zd);
  if (Enext) {  // layer 0 only: materialize E1 (fp32 + fp8 for next-layer gathers)
    const float en = z + zd + Eprev[j];
    Enext[j] = en;
    Enf8[j] = f2fp8(en);
  }
}

// ---------------- dual-dir SVD middle matrix, block-reduced atomics ----------------
__global__ __launch_bounds__(256) void svd_reduce2(
    const float* __restrict__ T0, const float* __restrict__ E0,
    const float* __restrict__ T1, const float* __restrict__ E1,
    float* __restrict__ Mu, float* __restrict__ Mi) {
  const int dir = blockIdx.y;
  const float* __restrict__ T = dir ? T1 : T0;
  const float* __restrict__ E = dir ? E1 : E0;
  float* __restrict__ M = dir ? Mi : Mu;
  const int lane = threadIdx.x & 63;
  const int wl = threadIdx.x >> 6;
  const int gw = blockIdx.x * 4 + wl;
  float a0 = 0.f, a1 = 0.f, a2 = 0.f, a3 = 0.f, a4 = 0.f;
  for (int i = gw; i < NROW; i += 4096) {
    const float x = E[(size_t)i * 64 + lane];
    a0 += T[i] * x;
    a1 += T[NROW + i] * x;
    a2 += T[2 * NROW + i] * x;
    a3 += T[3 * NROW + i] * x;
    a4 += T[4 * NROW + i] * x;
  }
  __shared__ float red[4][5][64];
  red[wl][0][lane] = a0; red[wl][1][lane] = a1; red[wl][2][lane] = a2;
  red[wl][3][lane] = a3; red[wl][4][lane] = a4;
  __syncthreads();
  for (int o = threadIdx.x; o < 320; o += 256) {
    const int q = o >> 6, d = o & 63;
    const float s = red[0][q][d] + red[1][q][d] + red[2][q][d] + red[3][q][d];
    atomicAdd(&M[o], s);
  }
}

// gather batch rows & L2-normalize -> bf16; blockIdx.y selects {Z, Zd, G}
__global__ __launch_bounds__(256) void gather_norm(
    const int* __restrict__ ids, const u16* __restrict__ Z,
    const u16* __restrict__ Zd, const float* __restrict__ mul_s,
    const float* __restrict__ M, u16* __restrict__ oZ,
    u16* __restrict__ oZd, u16* __restrict__ oG) {
  long long t = (long long)blockIdx.x * blockDim.x + threadIdx.x;
  int b = (int)(t >> 6);
  int d = (int)(t & 63);
  if (b >= C_B) return;
  int id = rfl(ids[b]);
  float v;
  u16* out;
  if (blockIdx.y == 0) { v = bf2f(Z[(size_t)id * 64 + d]); out = oZ; }
  else if (blockIdx.y == 1) { v = bf2f(Zd[(size_t)id * 64 + d]); out = oZd; }
  else {
    float s = 0.f;
#pragma unroll
    for (int q = 0; q < 5; ++q) s += mul_s[(size_t)id * 5 + q] * M[q * 64 + d];
    v = leaky(s);
    out = oG;
  }
  float ss = v * v;
#pragma unroll
  for (int off = 1; off < 64; off <<= 1) ss += __shfl_xor(ss, off);
  float nrm = fmaxf(sqrtf(ss), 1e-12f);
  out[(size_t)b * 64 + d] = f2bf(v / nrm);
}

// ---------------- MFMA hyper (LDS-free): hy = (X @ W) * log2e/TEMP ----------------
__global__ __launch_bounds__(256) void hyper_mfma(
    const u16* __restrict__ nb, const u16* __restrict__ Wt16,
    u16* __restrict__ hy) {
  const int call = blockIdx.y;
  const int b0 = blockIdx.x * 64;
  const int lane = threadIdx.x & 63, wid = threadIdx.x >> 6;
  const u16* X = nb + (size_t)c_hsrc[call] * C_B * 64;
  const u16* Wt = Wt16 + (size_t)c_wsel[call] * 4096;
  const int am = (wid << 4) + (lane & 15);
  const int ke = ((lane >> 4) << 3);  // fragment k-offset (elements)
  short8 af[2];
#pragma unroll
  for (int ks = 0; ks < 2; ++ks)
    af[ks] = *(const short8*)&X[(size_t)(b0 + am) * 64 + ks * 32 + ke];
  const int ob = b0 + (wid << 4) + ((lane >> 4) << 2);
#pragma unroll
  for (int n = 0; n < 4; ++n) {
    const int bn = (n << 4) + (lane & 15);
    f32x4 acc = {0.f, 0.f, 0.f, 0.f};
#pragma unroll
    for (int ks = 0; ks < 2; ++ks) {
      short8 bf = *(const short8*)&Wt[(size_t)bn * 64 + ks * 32 + ke];
      acc = __builtin_amdgcn_mfma_f32_16x16x32_bf16(af[ks], bf, acc, 0, 0, 0);
    }
    const int d = (n << 4) + (lane & 15);
#pragma unroll
    for (int j = 0; j < 4; ++j)
      hy[(size_t)call * C_B * 64 + (size_t)(ob + j) * 64 + d] =
          f2bf(acc[j] * 7.2134752f);  // fold log2(e)/TEMP into H
  }
}

// ---------------- MFMA info_nce partials: 128 g-rows x 16 H-tiles per block ----
// grid: (32 g-tiles, 4 jt-chunks, 16 calls); G fragments loaded direct from global
__global__ __launch_bounds__(256) void nce_partial(
    const u16* __restrict__ nb, const u16* __restrict__ hy,
    float* __restrict__ rsbuf, float* __restrict__ psbuf) {
  const int call = blockIdx.z;
  const int jc = blockIdx.y;
  const u16* G = nb + (size_t)c_gsel[call] * C_B * 64;
  const u16* H = hy + (size_t)call * C_B * 64;
  const int br = blockIdx.x * 128;
  const int jt0 = jc * 16;
  __shared__ u16 Hs[2][64 * 64];
  const int tid = threadIdx.x, lane = tid & 63, wid = tid >> 6;
  const int ke = ((lane >> 4) << 3);
  short8 bfG[2][2];
#pragma unroll
  for (int s = 0; s < 2; ++s)
#pragma unroll
    for (int ks = 0; ks < 2; ++ks) {
      const int gc = (wid << 5) + (s << 4) + (lane & 15);
      bfG[s][ks] = *(const short8*)&G[(size_t)(br + gc) * 64 + ks * 32 + ke];
    }
  const int r = tid >> 2, seg = tid & 3;
  const int base = r * 128 + seg * 32, sw = (r & 7) << 4;
  {
    const uint4* src = (const uint4*)&H[(size_t)(jt0 * 64 + r) * 64 + seg * 16];
    uint4 a = src[0], b = src[1];
    *(uint4*)((char*)Hs[0] + (base ^ sw)) = a;
    *(uint4*)((char*)Hs[0] + ((base + 16) ^ sw)) = b;
  }
  float rs[2] = {0.f, 0.f}, ps[2] = {0.f, 0.f};
  const int jt_diag = (blockIdx.x << 1) + (wid >> 1);
  const int hsd0 = (wid & 1) << 1;
  int cur = 0;
  for (int jt = jt0; jt < jt0 + 16; ++jt) {
    __syncthreads();  // Hs[cur] ready
    uint4 na, nb_;
    if (jt + 1 < jt0 + 16) {  // prefetch next H tile
      const uint4* src = (const uint4*)&H[(size_t)((jt + 1) * 64 + r) * 64 + seg * 16];
      na = src[0]; nb_ = src[1];
    }
    const bool dj = (jt == jt_diag);
    const char* Hb = (const char*)(Hs[cur]);
#pragma unroll
    for (int hs = 0; hs < 4; ++hs) {
      const int hr = (hs << 4) + (lane & 15);
      const int offA0 = (hr * 128 + ((lane >> 4) << 4)) ^ ((hr & 7) << 4);
      const int offA1 = (hr * 128 + 64 + ((lane >> 4) << 4)) ^ ((hr & 7) << 4);
      const short8 af0 = *(const short8*)(Hb + offA0);
      const short8 af1 = *(const short8*)(Hb + offA1);
      f32x4 acc0 = {0.f, 0.f, 0.f, 0.f}, acc1 = {0.f, 0.f, 0.f, 0.f};
      __builtin_amdgcn_s_setprio(1);
      acc0 = __builtin_amdgcn_mfma_f32_16x16x32_bf16(af0, bfG[0][0], acc0, 0, 0, 0);
      acc0 = __builtin_amdgcn_mfma_f32_16x16x32_bf16(af1, bfG[0][1], acc0, 0, 0, 0);
      acc1 = __builtin_amdgcn_mfma_f32_16x16x32_bf16(af0, bfG[1][0], acc1, 0, 0, 0);
      acc1 = __builtin_amdgcn_mfma_f32_16x16x32_bf16(af1, bfG[1][1], acc1, 0, 0, 0);
      __builtin_amdgcn_s_setprio(0);
      float e0[4], e1[4];
#pragma unroll
      for (int j = 0; j < 4; ++j) {
        e0[j] = fast_exp2(acc0[j]);  // H pre-scaled by log2e/TEMP
        e1[j] = fast_exp2(acc1[j]);
      }
      rs[0] += (e0[0] + e0[1]) + (e0[2] + e0[3]);
      rs[1] += (e1[0] + e1[1]) + (e1[2] + e1[3]);
      if (dj) {
        const int jm = (lane & 15) - ((lane >> 4) << 2);
        if (hs == hsd0) {
#pragma unroll
          for (int j = 0; j < 4; ++j)
            if (jm == j) ps[0] = e0[j];
        }
        if (hs == hsd0 + 1) {
#pragma unroll
          for (int j = 0; j < 4; ++j)
            if (jm == j) ps[1] = e1[j];
        }
      }
    }
    if (jt + 1 < jt0 + 16) {
      *(uint4*)((char*)Hs[cur ^ 1] + (base ^ sw)) = na;
      *(uint4*)((char*)Hs[cur ^ 1] + ((base + 16) ^ sw)) = nb_;
    }
    cur ^= 1;
  }
#pragma unroll
  for (int s = 0; s < 2; ++s) {
    rs[s] += __shfl_xor(rs[s], 16); rs[s] += __shfl_xor(rs[s], 32);
    ps[s] += __shfl_xor(ps[s], 16); ps[s] += __shfl_xor(ps[s], 32);
  }
  if ((lane >> 4) == 0) {
    const bool own_diag = ((jt_diag >> 4) == jc);  // wave-uniform
#pragma unroll
    for (int s = 0; s < 2; ++s) {
      const int gg = br + (wid << 5) + (s << 4) + (lane & 15);
      atomicAdd(&rsbuf[(size_t)call * C_B + gg], rs[s]);
      if (own_diag) psbuf[(size_t)call * C_B + gg] = ps[s];
    }
  }
}

// finalize: v = -log(ps/(rs+eps)+eps), mask, reduce to slots
__global__ __launch_bounds__(256) void nce_final(
    const float* __restrict__ rsbuf, const float* __restrict__ psbuf,
    float* __restrict__ slots, NceKeys nk) {
  const int call = blockIdx.y;
  const int g = blockIdx.x * 256 + threadIdx.x;
  const float rs = rsbuf[(size_t)call * C_B + g];
  const float ps = psbuf[(size_t)call * C_B + g];
  const float v = -__logf(ps / (rs + 1e-8f) + 1e-8f);
  const float u = tf_uniform(nk.k0[call], nk.k1[call], (uint32_t)g);
  float c = (u > 0.5f) ? v : 0.f;
#pragma unroll
  for (int off = 1; off < 64; off <<= 1) c += __shfl_xor(c, off);
  __shared__ float wsum[4];
  if ((threadIdx.x & 63) == 0) wsum[threadIdx.x >> 6] = c;
  __syncthreads();
  if (threadIdx.x == 0)
    atomicAdd(&slots[c_slot[call]], wsum[0] + wsum[1] + wsum[2] + wsum[3]);
}

// E_sum = E0 + 2*E1 + Z2 + Zd2  (E2 never materialized; Z in bf16)
__global__ __launch_bounds__(256) void loss_r_kernel(
    const float* __restrict__ E0u, const float* __restrict__ Eu1,
    const u16* __restrict__ Zu, const u16* __restrict__ Zdu,
    const float* __restrict__ E0i, const float* __restrict__ Ei1,
    const u16* __restrict__ Zi, const u16* __restrict__ Zdi,
    const int* __restrict__ uids, const int* __restrict__ pos,
    const int* __restrict__ neg, float* __restrict__ slots) {
  long long t = (long long)blockIdx.x * blockDim.x + threadIdx.x;
  int b = (int)(t >> 6);
  int d = (int)(t & 63);
  if (b >= C_B) return;
  size_t ju = (size_t)rfl(uids[b]) * 64 + d;
  float u = E0u[ju] + 2.f * Eu1[ju] + bf2f(Zu[ju]) + bf2f(Zdu[ju]);
  float bpr = 0.f, pmin = 3.4e38f, nmax = -3.4e38f;
  for (int p = 0; p < C_P; ++p) {
    size_t jp = (size_t)rfl(pos[b * C_P + p]) * 64 + d;
    size_t jn = (size_t)rfl(neg[b * C_P + p]) * 64 + d;
    float pe = E0i[jp] + 2.f * Ei1[jp] + bf2f(Zi[jp]) + bf2f(Zdi[jp]);
    float ne = E0i[jn] + 2.f * Ei1[jn] + bf2f(Zi[jn]) + bf2f(Zdi[jn]);
    float psc = u * pe, nsc = u * ne;
#pragma unroll
    for (int off = 1; off < 64; off <<= 1) {
      psc += __shfl_xor(psc, off);
      nsc += __shfl_xor(nsc, off);
    }
    pmin = fminf(pmin, psc);
    nmax = fmaxf(nmax, nsc);
    bpr += fmaxf(1.f - psc + nsc, 0.f);
  }
  if (d == 0) {
    float hd = (nmax - pmin > 0.005f) ? 10.f * (nmax - pmin) : 0.f;
    atomicAdd(&slots[5], bpr + hd);
  }
}

__global__ void final_kernel(const float* __restrict__ slots, float* __restrict__ out) {
  if (threadIdx.x == 0 && blockIdx.x == 0) {
    float n = slots[0], dl = slots[1], nn = slots[2], dd = slots[3], nd = slots[4];
    float lr = slots[5] / (float)C_B;
    out[0] = lr + 0.2f * (n + dl) + 0.2f * (nn + dd + nd);
    out[1] = lr;
    out[2] = dl;
    out[3] = n;
  }
}

// ---------------- host ----------------
extern "C" void kernel_launch(void* const* d_in, const int* in_sizes, int n_in,
                              void* d_out, int out_size, void* d_ws, size_t ws_size,
                              hipStream_t stream) {
  (void)in_sizes; (void)n_in; (void)out_size;
  const float* E_u_0   = (const float*)d_in[0];
  const float* E_i_0   = (const float*)d_in[1];
  const float* adjvals = (const float*)d_in[2];
  const float* u_mul_s = (const float*)d_in[3];
  const float* v_mul_s = (const float*)d_in[4];
  const float* ut      = (const float*)d_in[5];
  const float* vt      = (const float*)d_in[6];
  const float* W_nn    = (const float*)d_in[7];
  const float* W_dd    = (const float*)d_in[8];
  const float* W_ng    = (const float*)d_in[9];
  const float* W_dg    = (const float*)d_in[10];
  const float* W_nd    = (const float*)d_in[11];
  const int* adj_rows  = (const int*)d_in[12];
  const int* adj_cols  = (const int*)d_in[13];
  const int* uids      = (const int*)d_in[14];
  const int* iids      = (const int*)d_in[15];
  const int* pos       = (const int*)d_in[16];
  const int* neg       = (const int*)d_in[17];
  float* out = (float*)d_out;

  const size_t NU64 = (size_t)C_NU * 64;
  const size_t NI64 = (size_t)C_NI * 64;
  const size_t B64  = (size_t)C_B * 64;

  float* w = (float*)d_ws;
  float* Eu1 = w; w += NU64;
  float* Ei1 = w; w += NI64;
  u16* Zu  = (u16*)w;            // 4 contiguous bf16 Z buffers; edgesA aliases
  u16* Zdu = Zu + NU64;
  u16* Zi  = Zdu + NU64;
  u16* Zdi = Zi + NI64;
  w += 2 * NU64;                 // 4 * NU64 u16 = 2 * NU64 floats
  float* Mu = w; w += 512;
  float* Mi = w; w += 512;
  u16* normbuf16 = (u16*)w; w += 6 * B64;     // 12 bf16 buffers of B64
  float* slots = w; w += 16;
  uint2* edgesB = (uint2*)w; w += 4 * C_NE;   // 32 MB final CSR (both dirs)
  u16* hyper16 = (u16*)edgesB;                // alias: edgesB dead before hyper
  u16* Wt16 = (u16*)w; w += 16384;
  uint32_t* cntA = (uint32_t*)w; w += NCB * NCHK * 2;
  uint32_t* offs = (uint32_t*)w; w += NCB * NCHK * 2;
  uint32_t* bsumA = (uint32_t*)w; w += NCB;
  uint32_t* boffA = (uint32_t*)w; w += NCB;
  uint32_t* startsAbs = (uint32_t*)w; w += 2 * (NROW + 1);
  u8* Eu0f = (u8*)w; w += NU64 / 4;           // fp8 gather tables
  u8* Ei0f = (u8*)w; w += NI64 / 4;
  u8* Eu1f = (u8*)w; w += NU64 / 4;
  u8* Ei1f = Ei0f;                            // alias: Ei0f dead after layer 0
  float* rsbuf = w; w += 16 * C_B;            // nce partial denominators
  float* psbuf = w; w += 16 * C_B;            // nce diag numerators
  uint2* edgesA = (uint2*)Zu;                 // 32 MB coarse buffer (< Zu..Zi)
  if ((size_t)((char*)w - (char*)d_ws) > ws_size) return;

  // ---- host-side JAX key derivation (partitionable threefry) ----
  auto ksplit = [](uint32_t a, uint32_t b, uint32_t idx, uint32_t& o0, uint32_t& o1) {
    uint32_t x0 = 0u, x1 = idx;
    tf2x32(a, b, x0, x1);
    o0 = x0; o1 = x1;
  };
  uint32_t rk0 = 0u, rk1 = 42u;
  uint32_t lk[2][4][2];
  for (int l = 0; l < 2; ++l) {
    uint32_t n0, n1;
    ksplit(rk0, rk1, 0u, n0, n1);
    for (int i = 0; i < 4; ++i) ksplit(rk0, rk1, (uint32_t)(i + 1), lk[l][i][0], lk[l][i][1]);
    rk0 = n0; rk1 = n1;
  }
  NceKeys nk;
  {
    uint32_t mk0 = 0u, mk1 = 7u;
    for (int i = 0; i < 16; ++i) {
      uint32_t n0, n1;
      ksplit(mk0, mk1, 0u, n0, n1);
      ksplit(mk0, mk1, 1u, nk.k0[i], nk.k1[i]);
      mk0 = n0; mk1 = n1;
    }
  }
  DropKeys dk;
  dk.a[0] = lk[0][0][0]; dk.a[1] = lk[0][0][1];
  dk.a[2] = lk[1][0][0]; dk.a[3] = lk[1][0][1];
  dk.a[4] = lk[0][1][0]; dk.a[5] = lk[0][1][1];
  dk.a[6] = lk[1][1][0]; dk.a[7] = lk[1][1][1];
  WPtrs wp;
  wp.W[0] = W_ng; wp.W[1] = W_ng + 4096;
  wp.W[2] = W_nn;
  wp.W[3] = W_dg; wp.W[4] = W_dg + 4096;
  wp.W[5] = W_dd;
  wp.W[6] = W_nd; wp.W[7] = W_nd + 4096;

  // ---- sort + preps ----
  hipMemsetAsync(slots, 0, 16 * 4, stream);
  hipMemsetAsync(rsbuf, 0, 16 * C_B * 4, stream);
  passA_hist<<<dim3(NCHK, 2), 256, 0, stream>>>(adj_rows, adj_cols, cntA);
  scanA1<<<NCB, 512, 0, stream>>>(cntA, offs, bsumA);
  scanA2<<<1, 256, 0, stream>>>(bsumA, boffA);
  scanA3<<<NCB, 512, 0, stream>>>(offs, boffA);
  passA_scatter<<<dim3(NCHK, 2), 256, 0, stream>>>(
      adj_rows, adj_cols, adjvals, offs, edgesA, dk);
  passB_kernel<<<dim3(NCB, 2), 512, 0, stream>>>(edgesA, offs, edgesB, startsAbs);
  fp8_convert<<<(int)(NU64 / 4 + 255) / 256, 256, 0, stream>>>(E_u_0, Eu0f, (int)(NU64 / 4));
  fp8_convert<<<(int)(NI64 / 4 + 255) / 256, 256, 0, stream>>>(E_i_0, Ei0f, (int)(NI64 / 4));
  w16_prep<<<(8 * 4096 + 255) / 256, 256, 0, stream>>>(wp, Wt16);

  const int gb = (int)(B64 / 256);  // 1024
  const int sb = (NROW + 3) / 4;    // 25000 blocks, 4 waves each

  for (int l = 0; l < 2; ++l) {
    hipMemsetAsync(Mu, 0, 1024 * 4, stream);  // Mu+Mi contiguous
    svd_reduce2<<<dim3(1024, 2), 256, 0, stream>>>(
        vt, (l == 0) ? E_i_0 : Ei1, ut, (l == 0) ? E_u_0 : Eu1, Mu, Mi);
    // dir0: items -> users (noise key k3); one fp8 table live per dispatch
    spmm_row<<<sb, 256, 0, stream>>>(
        edgesB, startsAbs, (l == 0) ? Ei0f : Ei1f,
        (l == 0) ? E_u_0 : nullptr, (l == 0) ? Eu1 : nullptr,
        (l == 0) ? Eu1f : nullptr, Zu, Zdu, lk[l][2][0], lk[l][2][1], l);
    // dir1: users -> items (noise key k4)
    spmm_row<<<sb, 256, 0, stream>>>(
        edgesB, startsAbs + (NROW + 1), (l == 0) ? Eu0f : Eu1f,
        (l == 0) ? E_i_0 : nullptr, (l == 0) ? Ei1 : nullptr,
        (l == 0) ? Ei1f : nullptr, Zi, Zdi, lk[l][3][0], lk[l][3][1], l);
    gather_norm<<<dim3(gb, 3), 256, 0, stream>>>(
        uids, Zu, Zdu, u_mul_s, Mu,
        normbuf16 + (size_t)(0 + l) * B64, normbuf16 + (size_t)(4 + l) * B64,
        normbuf16 + (size_t)(8 + l) * B64);
    gather_norm<<<dim3(gb, 3), 256, 0, stream>>>(
        iids, Zi, Zdi, v_mul_s, Mi,
        normbuf16 + (size_t)(2 + l) * B64, normbuf16 + (size_t)(6 + l) * B64,
        normbuf16 + (size_t)(10 + l) * B64);
  }

  hyper_mfma<<<dim3(C_B / 64, 16), 256, 0, stream>>>(normbuf16, Wt16, hyper16);
  nce_partial<<<dim3(C_B / 128, 4, 16), 256, 0, stream>>>(normbuf16, hyper16,
                                                          rsbuf, psbuf);
  nce_final<<<dim3(C_B / 256, 16), 256, 0, stream>>>(rsbuf, psbuf, slots, nk);
  loss_r_kernel<<<gb, 256, 0, stream>>>(E_u_0, Eu1, Zu, Zdu, E_i_0, Ei1, Zi, Zdi,
                                        uids, pos, neg, slots);
  final_kernel<<<1, 1, 0, stream>>>(slots, out);
}

// Round 14
// 633.350 us; speedup vs baseline: 1.0092x; 1.0092x over previous
//
#include <hip/hip_runtime.h>
#include <hip/hip_bf16.h>
#include <cstdint>

#define C_NU 100000
#define C_NI 100000
#define C_DIM 64
#define C_Q 5
#define C_NE 2000000
#define C_B 4096
#define C_P 10
#define NROW 100000
#define NCB 196      // coarse buckets of 512 rows
#define NCHK 256     // chunks in pass A
#define CHUNK 7813   // ceil(2M/256)

typedef unsigned short u16;
typedef unsigned char u8;
typedef __attribute__((ext_vector_type(8))) short short8;
typedef __attribute__((ext_vector_type(4))) float f32x4;

__device__ static inline int rfl(int v) { return __builtin_amdgcn_readfirstlane(v); }
__device__ static inline uint32_t rflu(uint32_t v) {
  return (uint32_t)__builtin_amdgcn_readfirstlane((int)v);
}

// single-instruction exp2 (exp2f lowers to a slow OCML sequence without fast-math)
__device__ static inline float fast_exp2(float x) {
  float r;
  asm("v_exp_f32 %0, %1" : "=v"(r) : "v"(x));
  return r;
}

// ---------------- Threefry-2x32 (JAX-compatible), 20 rounds ----------------
__host__ __device__ static inline void tf2x32(uint32_t k0, uint32_t k1,
                                              uint32_t& x0, uint32_t& x1) {
  uint32_t k2 = k0 ^ k1 ^ 0x1BD11BDAu;
#define TFR(r) { x0 += x1; x1 = (x1 << r) | (x1 >> (32 - r)); x1 ^= x0; }
  x0 += k0; x1 += k1;
  TFR(13) TFR(15) TFR(26) TFR(6)
  x0 += k1; x1 += k2 + 1u;
  TFR(17) TFR(29) TFR(16) TFR(24)
  x0 += k2; x1 += k0 + 2u;
  TFR(13) TFR(15) TFR(26) TFR(6)
  x0 += k0; x1 += k1 + 3u;
  TFR(17) TFR(29) TFR(16) TFR(24)
  x0 += k1; x1 += k2 + 4u;
  TFR(13) TFR(15) TFR(26) TFR(6)
  x0 += k2; x1 += k0 + 5u;
#undef TFR
}

// partitionable-mode random bits at flat index idx (hi counter = 0)
__device__ static inline float tf_uniform(uint32_t k0, uint32_t k1, uint32_t idx) {
  uint32_t x0 = 0u, x1 = idx;
  tf2x32(k0, k1, x0, x1);
  uint32_t bits = x0 ^ x1;
  return __uint_as_float((bits >> 9) | 0x3F800000u) - 1.0f;
}

__device__ static inline float leaky(float x) { return x >= 0.f ? x : 0.5f * x; }

__device__ static inline u16 f2bf(float f) {  // RNE fp32->bf16
  uint32_t x = __float_as_uint(f);
  return (u16)((x + 0x7FFFu + ((x >> 16) & 1u)) >> 16);
}
__device__ static inline float bf2f(u16 u) {
  return __uint_as_float((uint32_t)u << 16);
}

// fp8 store: byte = sign | 7-bit (4-exp,3-mant) of (x*256), RNE, underflow->0.
__device__ static inline u8 f2fp8(float x) {
  float t = x * 256.f;
  uint32_t sgn = (__float_as_uint(t) >> 24) & 0x80u;
  float a = fabsf(t) * 0x1p-120f;
  uint32_t u = __float_as_uint(a);
  u += 0x7FFFFu + ((u >> 20) & 1u);
  uint32_t mag = u >> 20;
  if (mag > 0x7Fu) mag = 0x7Fu;
  return (u8)(sgn | mag);
}
__device__ static inline float fp8dec(uint32_t b) {  // * 2^-112 folded into weight
  return __uint_as_float(((b & 0x80u) << 24) | ((b & 0x7Fu) << 20));
}

// ---------------- constant maps for the 16 info_nce calls ----------------
// normbuf slots: 0:Zu1 1:Zu2 2:Zi1 3:Zi2 4:Zdu1 5:Zdu2 6:Zdi1 7:Zdi2 8:Gu1 9:Gu2 10:Gi1 11:Gi2
__constant__ int c_gsel[16] = {0,1,2,3, 0,2, 4,5,6,7, 4,6, 0,1,2,3};
__constant__ int c_hsrc[16] = {8,9,10,11, 1,3, 8,9,10,11, 5,7, 4,5,6,7};
// W order: 0:ng0 1:ng1 2:nn 3:dg0 4:dg1 5:dd 6:nd0 7:nd1
__constant__ int c_wsel[16] = {0,1,0,1, 2,2, 3,4,3,4, 5,5, 6,7,6,7};
// slots: 0:n 1:d 2:nn 3:dd 4:nd (5: loss_r sum)
__constant__ int c_slot[16] = {0,0,0,0, 2,2, 1,1,1,1, 3,3, 4,4,4,4};

struct WPtrs { const float* W[8]; };
struct NceKeys { uint32_t k0[16]; uint32_t k1[16]; };
struct DropKeys { uint32_t a[8]; };
struct SpmmArgs {
  const u8* Einf[2];
  const float* Eprev[2];
  float* Enext[2];
  u8* Enf8[2];
  u16* Z[2];
  u16* Zd[2];
  uint32_t nk[2][2];
};

// ---------------- two-level counting sort ----------------

__global__ __launch_bounds__(256) void passA_hist(
    const int* __restrict__ rows, const int* __restrict__ cols,
    uint32_t* __restrict__ cntA) {
  __shared__ uint32_t h[NCB];
  const int dir = blockIdx.y, c = blockIdx.x, t = threadIdx.x;
  for (int i = t; i < NCB; i += 256) h[i] = 0u;
  __syncthreads();
  const int e0 = c * CHUNK, e1 = min(e0 + CHUNK, C_NE);
  const int* ids = dir ? cols : rows;
  for (int e = e0 + t; e < e1; e += 256) atomicAdd(&h[ids[e] >> 9], 1u);
  __syncthreads();
  for (int i = t; i < NCB; i += 256) cntA[(dir * NCB + i) * NCHK + c] = h[i];
}

__global__ __launch_bounds__(512) void scanA1(
    const uint32_t* __restrict__ cntA, uint32_t* __restrict__ offs,
    uint32_t* __restrict__ bsum) {
  __shared__ uint32_t s[512];
  const int b = blockIdx.x, t = threadIdx.x;
  const int idx = b * 512 + t;
  uint32_t v = cntA[idx];
  s[t] = v;
  __syncthreads();
  for (int off = 1; off < 512; off <<= 1) {
    uint32_t a = (t >= off) ? s[t - off] : 0u;
    __syncthreads();
    s[t] += a;
    __syncthreads();
  }
  offs[idx] = s[t] - v;
  if (t == 511) bsum[b] = s[511];
}

__global__ __launch_bounds__(256) void scanA2(
    const uint32_t* __restrict__ bsum, uint32_t* __restrict__ boff) {
  __shared__ uint32_t s[256];
  const int t = threadIdx.x;
  uint32_t v = (t < NCB) ? bsum[t] : 0u;
  s[t] = v;
  __syncthreads();
  for (int off = 1; off < 256; off <<= 1) {
    uint32_t a = (t >= off) ? s[t - off] : 0u;
    __syncthreads();
    s[t] += a;
    __syncthreads();
  }
  if (t < NCB) boff[t] = s[t] - v;
}

__global__ __launch_bounds__(512) void scanA3(
    uint32_t* __restrict__ offs, const uint32_t* __restrict__ boff) {
  offs[blockIdx.x * 512 + threadIdx.x] += boff[blockIdx.x];
}

// record.x = src(17b) | keepL0<<17 | keepL1<<18 | (dst&511)<<19
// record.y = vals[e] * 2^112 (fp8 decode scale pre-folded)
__global__ __launch_bounds__(256) void passA_scatter(
    const int* __restrict__ rows, const int* __restrict__ cols,
    const float* __restrict__ vals, const uint32_t* __restrict__ offs,
    uint2* __restrict__ edgesA, DropKeys dk) {
  __shared__ uint32_t lofs[NCB];
  const int dir = blockIdx.y, c = blockIdx.x, t = threadIdx.x;
  for (int i = t; i < NCB; i += 256) lofs[i] = offs[(dir * NCB + i) * NCHK + c];
  __syncthreads();
  const int e0 = c * CHUNK, e1 = min(e0 + CHUNK, C_NE);
  const uint32_t kA0 = dk.a[dir * 4 + 0], kA1 = dk.a[dir * 4 + 1];
  const uint32_t kB0 = dk.a[dir * 4 + 2], kB1 = dk.a[dir * 4 + 3];
  for (int e = e0 + t; e < e1; e += 256) {
    const int r = rows[e], cc = cols[e];
    const int dst = dir ? cc : r, src = dir ? r : cc;
    const uint32_t kl0 = (tf_uniform(kA0, kA1, (uint32_t)e) < 0.9f) ? 1u : 0u;
    const uint32_t kl1 = (tf_uniform(kB0, kB1, (uint32_t)e) < 0.9f) ? 1u : 0u;
    const uint32_t x = (uint32_t)src | (kl0 << 17) | (kl1 << 18) |
                       ((uint32_t)(dst & 511) << 19);
    const uint32_t pos = atomicAdd(&lofs[dst >> 9], 1u);
    edgesA[pos] = make_uint2(x, __float_as_uint(vals[e] * 0x1p112f));
  }
}

__global__ __launch_bounds__(512) void passB_kernel(
    const uint2* __restrict__ edgesA, const uint32_t* __restrict__ offs,
    uint2* __restrict__ edgesB, uint32_t* __restrict__ starts) {
  __shared__ uint32_t cnt[512];
  __shared__ uint32_t scn[512];
  const int dir = blockIdx.y, cb = blockIdx.x, t = threadIdx.x;
  const uint32_t segStart = offs[(dir * NCB + cb) * NCHK];
  const uint32_t segEnd = (dir == 1 && cb == NCB - 1)
                              ? (uint32_t)(2 * C_NE)
                              : offs[(dir * NCB + cb + 1) * NCHK];
  cnt[t] = 0u;
  __syncthreads();
  for (uint32_t e = segStart + t; e < segEnd; e += 512)
    atomicAdd(&cnt[(edgesA[e].x >> 19) & 511u], 1u);
  __syncthreads();
  uint32_t v = cnt[t];
  scn[t] = v;
  __syncthreads();
  for (int off = 1; off < 512; off <<= 1) {
    uint32_t a = (t >= off) ? scn[t - off] : 0u;
    __syncthreads();
    scn[t] += a;
    __syncthreads();
  }
  const uint32_t rstart = segStart + scn[t] - v;
  const int grow = cb * 512 + t;
  if (grow < NROW) starts[dir * (NROW + 1) + grow] = rstart;
  if (cb == NCB - 1 && t == 0) starts[dir * (NROW + 1) + NROW] = segEnd;
  cnt[t] = rstart;
  __syncthreads();
  for (uint32_t e = segStart + t; e < segEnd; e += 512) {
    const uint2 q = edgesA[e];
    const uint32_t pos = atomicAdd(&cnt[(q.x >> 19) & 511u], 1u);
    edgesB[pos] = q;
  }
}

// ---------------- fp32 -> fp8 table convert ----------------
__global__ __launch_bounds__(256) void fp8_convert(
    const float* __restrict__ src, u8* __restrict__ dst, int n4) {
  int i = blockIdx.x * 256 + threadIdx.x;
  if (i >= n4) return;
  float4 v = ((const float4*)src)[i];
  uint32_t o = (uint32_t)f2fp8(v.x) | ((uint32_t)f2fp8(v.y) << 8) |
               ((uint32_t)f2fp8(v.z) << 16) | ((uint32_t)f2fp8(v.w) << 24);
  ((uint32_t*)dst)[i] = o;
}

// Wt16[w][d][k] = bf16(W[w][k][d])  (pre-transposed for MFMA B-operand)
__global__ __launch_bounds__(256) void w16_prep(WPtrs wp, u16* __restrict__ Wt16) {
  int i = blockIdx.x * 256 + threadIdx.x;
  if (i >= 8 * 4096) return;
  int w = i >> 12, kd = i & 4095, k = kd >> 6, d = kd & 63;
  Wt16[w * 4096 + d * 64 + k] = f2bf(wp.W[w][k * 64 + d]);
}

// ---------------- fused spmm (wave/row, scalarized, fp8, both dirs) ----------------
__global__ __launch_bounds__(256) void spmm_row(
    const uint2* __restrict__ edges, const uint32_t* __restrict__ startsAbs,
    SpmmArgs a, int layer) {
  const int dir = blockIdx.y;
  const int row = rfl(blockIdx.x * 4 + (threadIdx.x >> 6));
  const int lane = threadIdx.x & 63;
  if (row >= NROW) return;
  const uint32_t* starts = startsAbs + dir * (NROW + 1);
  const u8* __restrict__ Einf = a.Einf[dir];
  const uint32_t s0 = rflu(starts[row]);
  const uint32_t s1 = rflu(starts[row + 1]);
  const uint32_t kbit = 1u << (17 + layer);
  float z = 0.f, zd = 0.f;
  uint32_t e = s0;
  for (; e + 4 <= s1; e += 4) {
    const uint32_t p0 = rflu(edges[e].x),     w0 = rflu(edges[e].y);
    const uint32_t p1 = rflu(edges[e + 1].x), w1 = rflu(edges[e + 1].y);
    const uint32_t p2 = rflu(edges[e + 2].x), w2 = rflu(edges[e + 2].y);
    const uint32_t p3 = rflu(edges[e + 3].x), w3 = rflu(edges[e + 3].y);
    const uint32_t b0 = Einf[(size_t)(p0 & 0x1FFFFu) * 64 + lane];
    const uint32_t b1 = Einf[(size_t)(p1 & 0x1FFFFu) * 64 + lane];
    const uint32_t b2 = Einf[(size_t)(p2 & 0x1FFFFu) * 64 + lane];
    const uint32_t b3 = Einf[(size_t)(p3 & 0x1FFFFu) * 64 + lane];
    const float x0 = fp8dec(b0), x1 = fp8dec(b1);
    const float x2 = fp8dec(b2), x3 = fp8dec(b3);
    const float v0 = __uint_as_float(w0), v1 = __uint_as_float(w1);
    const float v2 = __uint_as_float(w2), v3 = __uint_as_float(w3);
    const float d0 = (p0 & kbit) ? v0 : 0.f;
    const float d1 = (p1 & kbit) ? v1 : 0.f;
    const float d2 = (p2 & kbit) ? v2 : 0.f;
    const float d3 = (p3 & kbit) ? v3 : 0.f;
    z += v0 * x0; zd += d0 * x0;
    z += v1 * x1; zd += d1 * x1;
    z += v2 * x2; zd += d2 * x2;
    z += v3 * x3; zd += d3 * x3;
  }
  for (; e < s1; ++e) {
    const uint32_t p = rflu(edges[e].x), wv = rflu(edges[e].y);
    const float x = fp8dec(Einf[(size_t)(p & 0x1FFFFu) * 64 + lane]);
    const float v = __uint_as_float(wv);
    z += v * x;
    zd += ((p & kbit) ? v : 0.f) * x;
  }
  z = leaky(z);
  zd = leaky(zd * (1.0f / 0.9f));
  // noise-augmented view
  const float u = tf_uniform(a.nk[dir][0], a.nk[dir][1],
                             (uint32_t)row * 64u + (uint32_t)lane);
  float ss = u * u;
#pragma unroll
  for (int off = 1; off < 64; off <<= 1) ss += __shfl_xor(ss, off);
  const float nrm = fmaxf(sqrtf(ss), 1e-12f);
  const float sg = (z > 0.f) ? 1.f : (z < 0.f ? -1.f : 0.f);
  z += sg * (u / nrm) * 0.1f;
  const size_t j = (size_t)row * 64 + lane;
  a.Z[dir][j] = f2bf(z);
  a.Zd[dir][j] = f2bf(zd);
  if (a.Enext[dir]) {  // layer 0 only
    const float en = z + zd + a.Eprev[dir][j];
    a.Enext[dir][j] = en;
    a.Enf8[dir][j] = f2fp8(en);
  }
}

// ---------------- dual-dir SVD middle matrix, block-reduced atomics ----------------
__global__ __launch_bounds__(256) void svd_reduce2(
    const float* __restrict__ T0, const float* __restrict__ E0,
    const float* __restrict__ T1, const float* __restrict__ E1,
    float* __restrict__ Mu, float* __restrict__ Mi) {
  const int dir = blockIdx.y;
  const float* __restrict__ T = dir ? T1 : T0;
  const float* __restrict__ E = dir ? E1 : E0;
  float* __restrict__ M = dir ? Mi : Mu;
  const int lane = threadIdx.x & 63;
  const int wl = threadIdx.x >> 6;
  const int gw = blockIdx.x * 4 + wl;
  float a0 = 0.f, a1 = 0.f, a2 = 0.f, a3 = 0.f, a4 = 0.f;
  for (int i = gw; i < NROW; i += 4096) {
    const float x = E[(size_t)i * 64 + lane];
    a0 += T[i] * x;
    a1 += T[NROW + i] * x;
    a2 += T[2 * NROW + i] * x;
    a3 += T[3 * NROW + i] * x;
    a4 += T[4 * NROW + i] * x;
  }
  __shared__ float red[4][5][64];
  red[wl][0][lane] = a0; red[wl][1][lane] = a1; red[wl][2][lane] = a2;
  red[wl][3][lane] = a3; red[wl][4][lane] = a4;
  __syncthreads();
  for (int o = threadIdx.x; o < 320; o += 256) {
    const int q = o >> 6, d = o & 63;
    const float s = red[0][q][d] + red[1][q][d] + red[2][q][d] + red[3][q][d];
    atomicAdd(&M[o], s);
  }
}

// gather batch rows & L2-normalize -> bf16; blockIdx.y selects {Z, Zd, G}
__global__ __launch_bounds__(256) void gather_norm(
    const int* __restrict__ ids, const u16* __restrict__ Z,
    const u16* __restrict__ Zd, const float* __restrict__ mul_s,
    const float* __restrict__ M, u16* __restrict__ oZ,
    u16* __restrict__ oZd, u16* __restrict__ oG) {
  long long t = (long long)blockIdx.x * blockDim.x + threadIdx.x;
  int b = (int)(t >> 6);
  int d = (int)(t & 63);
  if (b >= C_B) return;
  int id = rfl(ids[b]);
  float v;
  u16* out;
  if (blockIdx.y == 0) { v = bf2f(Z[(size_t)id * 64 + d]); out = oZ; }
  else if (blockIdx.y == 1) { v = bf2f(Zd[(size_t)id * 64 + d]); out = oZd; }
  else {
    float s = 0.f;
#pragma unroll
    for (int q = 0; q < 5; ++q) s += mul_s[(size_t)id * 5 + q] * M[q * 64 + d];
    v = leaky(s);
    out = oG;
  }
  float ss = v * v;
#pragma unroll
  for (int off = 1; off < 64; off <<= 1) ss += __shfl_xor(ss, off);
  float nrm = fmaxf(sqrtf(ss), 1e-12f);
  out[(size_t)b * 64 + d] = f2bf(v / nrm);
}

// ---------------- MFMA hyper (LDS-free): hy = (X @ W) * log2e/TEMP ----------------
__global__ __launch_bounds__(256) void hyper_mfma(
    const u16* __restrict__ nb, const u16* __restrict__ Wt16,
    u16* __restrict__ hy) {
  const int call = blockIdx.y;
  const int b0 = blockIdx.x * 64;
  const int lane = threadIdx.x & 63, wid = threadIdx.x >> 6;
  const u16* X = nb + (size_t)c_hsrc[call] * C_B * 64;
  const u16* Wt = Wt16 + (size_t)c_wsel[call] * 4096;
  const int am = (wid << 4) + (lane & 15);
  const int ke = ((lane >> 4) << 3);  // fragment k-offset (elements)
  short8 af[2];
#pragma unroll
  for (int ks = 0; ks < 2; ++ks)
    af[ks] = *(const short8*)&X[(size_t)(b0 + am) * 64 + ks * 32 + ke];
  const int ob = b0 + (wid << 4) + ((lane >> 4) << 2);
#pragma unroll
  for (int n = 0; n < 4; ++n) {
    const int bn = (n << 4) + (lane & 15);
    f32x4 acc = {0.f, 0.f, 0.f, 0.f};
#pragma unroll
    for (int ks = 0; ks < 2; ++ks) {
      short8 bf = *(const short8*)&Wt[(size_t)bn * 64 + ks * 32 + ke];
      acc = __builtin_amdgcn_mfma_f32_16x16x32_bf16(af[ks], bf, acc, 0, 0, 0);
    }
    const int d = (n << 4) + (lane & 15);
#pragma unroll
    for (int j = 0; j < 4; ++j)
      hy[(size_t)call * C_B * 64 + (size_t)(ob + j) * 64 + d] =
          f2bf(acc[j] * 7.2134752f);  // fold log2(e)/TEMP into H
  }
}

// ---------------- MFMA info_nce partials: 128 g-rows x 16 H-tiles per block ----
// grid: (32 g-tiles, 4 jt-chunks, 16 calls); G fragments loaded direct from global
__global__ __launch_bounds__(256) void nce_partial(
    const u16* __restrict__ nb, const u16* __restrict__ hy,
    float* __restrict__ rsbuf, float* __restrict__ psbuf) {
  const int call = blockIdx.z;
  const int jc = blockIdx.y;
  const u16* G = nb + (size_t)c_gsel[call] * C_B * 64;
  const u16* H = hy + (size_t)call * C_B * 64;
  const int br = blockIdx.x * 128;
  const int jt0 = jc * 16;
  __shared__ u16 Hs[2][64 * 64];
  const int tid = threadIdx.x, lane = tid & 63, wid = tid >> 6;
  const int ke = ((lane >> 4) << 3);
  short8 bfG[2][2];
#pragma unroll
  for (int s = 0; s < 2; ++s)
#pragma unroll
    for (int ks = 0; ks < 2; ++ks) {
      const int gc = (wid << 5) + (s << 4) + (lane & 15);
      bfG[s][ks] = *(const short8*)&G[(size_t)(br + gc) * 64 + ks * 32 + ke];
    }
  const int r = tid >> 2, seg = tid & 3;
  const int base = r * 128 + seg * 32, sw = (r & 7) << 4;
  {
    const uint4* src = (const uint4*)&H[(size_t)(jt0 * 64 + r) * 64 + seg * 16];
    uint4 a = src[0], b = src[1];
    *(uint4*)((char*)Hs[0] + (base ^ sw)) = a;
    *(uint4*)((char*)Hs[0] + ((base + 16) ^ sw)) = b;
  }
  float rs[2] = {0.f, 0.f}, ps[2] = {0.f, 0.f};
  const int jt_diag = (blockIdx.x << 1) + (wid >> 1);
  const int hsd0 = (wid & 1) << 1;
  int cur = 0;
  for (int jt = jt0; jt < jt0 + 16; ++jt) {
    __syncthreads();  // Hs[cur] ready
    uint4 na, nb_;
    if (jt + 1 < jt0 + 16) {  // prefetch next H tile
      const uint4* src = (const uint4*)&H[(size_t)((jt + 1) * 64 + r) * 64 + seg * 16];
      na = src[0]; nb_ = src[1];
    }
    const bool dj = (jt == jt_diag);
    const char* Hb = (const char*)(Hs[cur]);
#pragma unroll
    for (int hs = 0; hs < 4; ++hs) {
      const int hr = (hs << 4) + (lane & 15);
      const int offA0 = (hr * 128 + ((lane >> 4) << 4)) ^ ((hr & 7) << 4);
      const int offA1 = (hr * 128 + 64 + ((lane >> 4) << 4)) ^ ((hr & 7) << 4);
      const short8 af0 = *(const short8*)(Hb + offA0);
      const short8 af1 = *(const short8*)(Hb + offA1);
      f32x4 acc0 = {0.f, 0.f, 0.f, 0.f}, acc1 = {0.f, 0.f, 0.f, 0.f};
      __builtin_amdgcn_s_setprio(1);
      acc0 = __builtin_amdgcn_mfma_f32_16x16x32_bf16(af0, bfG[0][0], acc0, 0, 0, 0);
      acc0 = __builtin_amdgcn_mfma_f32_16x16x32_bf16(af1, bfG[0][1], acc0, 0, 0, 0);
      acc1 = __builtin_amdgcn_mfma_f32_16x16x32_bf16(af0, bfG[1][0], acc1, 0, 0, 0);
      acc1 = __builtin_amdgcn_mfma_f32_16x16x32_bf16(af1, bfG[1][1], acc1, 0, 0, 0);
      __builtin_amdgcn_s_setprio(0);
      float e0[4], e1[4];
#pragma unroll
      for (int j = 0; j < 4; ++j) {
        e0[j] = fast_exp2(acc0[j]);  // H pre-scaled by log2e/TEMP
        e1[j] = fast_exp2(acc1[j]);
      }
      rs[0] += (e0[0] + e0[1]) + (e0[2] + e0[3]);
      rs[1] += (e1[0] + e1[1]) + (e1[2] + e1[3]);
      if (dj) {
        const int jm = (lane & 15) - ((lane >> 4) << 2);
        if (hs == hsd0) {
#pragma unroll
          for (int j = 0; j < 4; ++j)
            if (jm == j) ps[0] = e0[j];
        }
        if (hs == hsd0 + 1) {
#pragma unroll
          for (int j = 0; j < 4; ++j)
            if (jm == j) ps[1] = e1[j];
        }
      }
    }
    if (jt + 1 < jt0 + 16) {
      *(uint4*)((char*)Hs[cur ^ 1] + (base ^ sw)) = na;
      *(uint4*)((char*)Hs[cur ^ 1] + ((base + 16) ^ sw)) = nb_;
    }
    cur ^= 1;
  }
#pragma unroll
  for (int s = 0; s < 2; ++s) {
    rs[s] += __shfl_xor(rs[s], 16); rs[s] += __shfl_xor(rs[s], 32);
    ps[s] += __shfl_xor(ps[s], 16); ps[s] += __shfl_xor(ps[s], 32);
  }
  if ((lane >> 4) == 0) {
    const bool own_diag = ((jt_diag >> 4) == jc);  // wave-uniform
#pragma unroll
    for (int s = 0; s < 2; ++s) {
      const int gg = br + (wid << 5) + (s << 4) + (lane & 15);
      atomicAdd(&rsbuf[(size_t)call * C_B + gg], rs[s]);
      if (own_diag) psbuf[(size_t)call * C_B + gg] = ps[s];
    }
  }
}

// finalize: v = -log(ps/(rs+eps)+eps), mask, reduce to slots
__global__ __launch_bounds__(256) void nce_final(
    const float* __restrict__ rsbuf, const float* __restrict__ psbuf,
    float* __restrict__ slots, NceKeys nk) {
  const int call = blockIdx.y;
  const int g = blockIdx.x * 256 + threadIdx.x;
  const float rs = rsbuf[(size_t)call * C_B + g];
  const float ps = psbuf[(size_t)call * C_B + g];
  const float v = -__logf(ps / (rs + 1e-8f) + 1e-8f);
  const float u = tf_uniform(nk.k0[call], nk.k1[call], (uint32_t)g);
  float c = (u > 0.5f) ? v : 0.f;
#pragma unroll
  for (int off = 1; off < 64; off <<= 1) c += __shfl_xor(c, off);
  __shared__ float wsum[4];
  if ((threadIdx.x & 63) == 0) wsum[threadIdx.x >> 6] = c;
  __syncthreads();
  if (threadIdx.x == 0)
    atomicAdd(&slots[c_slot[call]], wsum[0] + wsum[1] + wsum[2] + wsum[3]);
}

// E_sum = E0 + 2*E1 + Z2 + Zd2  (E2 never materialized; Z in bf16)
__global__ __launch_bounds__(256) void loss_r_kernel(
    const float* __restrict__ E0u, const float* __restrict__ Eu1,
    const u16* __restrict__ Zu, const u16* __restrict__ Zdu,
    const float* __restrict__ E0i, const float* __restrict__ Ei1,
    const u16* __restrict__ Zi, const u16* __restrict__ Zdi,
    const int* __restrict__ uids, const int* __restrict__ pos,
    const int* __restrict__ neg, float* __restrict__ slots) {
  long long t = (long long)blockIdx.x * blockDim.x + threadIdx.x;
  int b = (int)(t >> 6);
  int d = (int)(t & 63);
  if (b >= C_B) return;
  size_t ju = (size_t)rfl(uids[b]) * 64 + d;
  float u = E0u[ju] + 2.f * Eu1[ju] + bf2f(Zu[ju]) + bf2f(Zdu[ju]);
  float bpr = 0.f, pmin = 3.4e38f, nmax = -3.4e38f;
  for (int p = 0; p < C_P; ++p) {
    size_t jp = (size_t)rfl(pos[b * C_P + p]) * 64 + d;
    size_t jn = (size_t)rfl(neg[b * C_P + p]) * 64 + d;
    float pe = E0i[jp] + 2.f * Ei1[jp] + bf2f(Zi[jp]) + bf2f(Zdi[jp]);
    float ne = E0i[jn] + 2.f * Ei1[jn] + bf2f(Zi[jn]) + bf2f(Zdi[jn]);
    float psc = u * pe, nsc = u * ne;
#pragma unroll
    for (int off = 1; off < 64; off <<= 1) {
      psc += __shfl_xor(psc, off);
      nsc += __shfl_xor(nsc, off);
    }
    pmin = fminf(pmin, psc);
    nmax = fmaxf(nmax, nsc);
    bpr += fmaxf(1.f - psc + nsc, 0.f);
  }
  if (d == 0) {
    float hd = (nmax - pmin > 0.005f) ? 10.f * (nmax - pmin) : 0.f;
    atomicAdd(&slots[5], bpr + hd);
  }
}

__global__ void final_kernel(const float* __restrict__ slots, float* __restrict__ out) {
  if (threadIdx.x == 0 && blockIdx.x == 0) {
    float n = slots[0], dl = slots[1], nn = slots[2], dd = slots[3], nd = slots[4];
    float lr = slots[5] / (float)C_B;
    out[0] = lr + 0.2f * (n + dl) + 0.2f * (nn + dd + nd);
    out[1] = lr;
    out[2] = dl;
    out[3] = n;
  }
}

// ---------------- host ----------------
extern "C" void kernel_launch(void* const* d_in, const int* in_sizes, int n_in,
                              void* d_out, int out_size, void* d_ws, size_t ws_size,
                              hipStream_t stream) {
  (void)in_sizes; (void)n_in; (void)out_size;
  const float* E_u_0   = (const float*)d_in[0];
  const float* E_i_0   = (const float*)d_in[1];
  const float* adjvals = (const float*)d_in[2];
  const float* u_mul_s = (const float*)d_in[3];
  const float* v_mul_s = (const float*)d_in[4];
  const float* ut      = (const float*)d_in[5];
  const float* vt      = (const float*)d_in[6];
  const float* W_nn    = (const float*)d_in[7];
  const float* W_dd    = (const float*)d_in[8];
  const float* W_ng    = (const float*)d_in[9];
  const float* W_dg    = (const float*)d_in[10];
  const float* W_nd    = (const float*)d_in[11];
  const int* adj_rows  = (const int*)d_in[12];
  const int* adj_cols  = (const int*)d_in[13];
  const int* uids      = (const int*)d_in[14];
  const int* iids      = (const int*)d_in[15];
  const int* pos       = (const int*)d_in[16];
  const int* neg       = (const int*)d_in[17];
  float* out = (float*)d_out;

  const size_t NU64 = (size_t)C_NU * 64;
  const size_t NI64 = (size_t)C_NI * 64;
  const size_t B64  = (size_t)C_B * 64;

  float* w = (float*)d_ws;
  float* Eu1 = w; w += NU64;
  float* Ei1 = w; w += NI64;
  u16* Zu  = (u16*)w;            // 4 contiguous bf16 Z buffers; edgesA aliases
  u16* Zdu = Zu + NU64;
  u16* Zi  = Zdu + NU64;
  u16* Zdi = Zi + NI64;
  w += 2 * NU64;                 // 4 * NU64 u16 = 2 * NU64 floats
  float* Mu = w; w += 512;
  float* Mi = w; w += 512;
  u16* normbuf16 = (u16*)w; w += 6 * B64;     // 12 bf16 buffers of B64
  float* slots = w; w += 16;
  uint2* edgesB = (uint2*)w; w += 4 * C_NE;   // 32 MB final CSR (both dirs)
  u16* hyper16 = (u16*)edgesB;                // alias: edgesB dead before hyper
  u16* Wt16 = (u16*)w; w += 16384;
  uint32_t* cntA = (uint32_t*)w; w += NCB * NCHK * 2;
  uint32_t* offs = (uint32_t*)w; w += NCB * NCHK * 2;
  uint32_t* bsumA = (uint32_t*)w; w += NCB;
  uint32_t* boffA = (uint32_t*)w; w += NCB;
  uint32_t* startsAbs = (uint32_t*)w; w += 2 * (NROW + 1);
  u8* Eu0f = (u8*)w; w += NU64 / 4;           // fp8 gather tables
  u8* Ei0f = (u8*)w; w += NI64 / 4;
  u8* Eu1f = (u8*)w; w += NU64 / 4;
  u8* Ei1f = Ei0f;                            // alias: Ei0f dead after layer 0
  float* rsbuf = w; w += 16 * C_B;            // nce partial denominators
  float* psbuf = w; w += 16 * C_B;            // nce diag numerators
  uint2* edgesA = (uint2*)Zu;                 // 32 MB coarse buffer (< Zu..Zi)
  if ((size_t)((char*)w - (char*)d_ws) > ws_size) return;

  // ---- host-side JAX key derivation (partitionable threefry) ----
  auto ksplit = [](uint32_t a, uint32_t b, uint32_t idx, uint32_t& o0, uint32_t& o1) {
    uint32_t x0 = 0u, x1 = idx;
    tf2x32(a, b, x0, x1);
    o0 = x0; o1 = x1;
  };
  uint32_t rk0 = 0u, rk1 = 42u;
  uint32_t lk[2][4][2];
  for (int l = 0; l < 2; ++l) {
    uint32_t n0, n1;
    ksplit(rk0, rk1, 0u, n0, n1);
    for (int i = 0; i < 4; ++i) ksplit(rk0, rk1, (uint32_t)(i + 1), lk[l][i][0], lk[l][i][1]);
    rk0 = n0; rk1 = n1;
  }
  NceKeys nk;
  {
    uint32_t mk0 = 0u, mk1 = 7u;
    for (int i = 0; i < 16; ++i) {
      uint32_t n0, n1;
      ksplit(mk0, mk1, 0u, n0, n1);
      ksplit(mk0, mk1, 1u, nk.k0[i], nk.k1[i]);
      mk0 = n0; mk1 = n1;
    }
  }
  DropKeys dk;
  dk.a[0] = lk[0][0][0]; dk.a[1] = lk[0][0][1];
  dk.a[2] = lk[1][0][0]; dk.a[3] = lk[1][0][1];
  dk.a[4] = lk[0][1][0]; dk.a[5] = lk[0][1][1];
  dk.a[6] = lk[1][1][0]; dk.a[7] = lk[1][1][1];
  WPtrs wp;
  wp.W[0] = W_ng; wp.W[1] = W_ng + 4096;
  wp.W[2] = W_nn;
  wp.W[3] = W_dg; wp.W[4] = W_dg + 4096;
  wp.W[5] = W_dd;
  wp.W[6] = W_nd; wp.W[7] = W_nd + 4096;

  // ---- sort + preps ----
  hipMemsetAsync(slots, 0, 16 * 4, stream);
  hipMemsetAsync(rsbuf, 0, 16 * C_B * 4, stream);
  passA_hist<<<dim3(NCHK, 2), 256, 0, stream>>>(adj_rows, adj_cols, cntA);
  scanA1<<<NCB, 512, 0, stream>>>(cntA, offs, bsumA);
  scanA2<<<1, 256, 0, stream>>>(bsumA, boffA);
  scanA3<<<NCB, 512, 0, stream>>>(offs, boffA);
  passA_scatter<<<dim3(NCHK, 2), 256, 0, stream>>>(
      adj_rows, adj_cols, adjvals, offs, edgesA, dk);
  passB_kernel<<<dim3(NCB, 2), 512, 0, stream>>>(edgesA, offs, edgesB, startsAbs);
  fp8_convert<<<(int)(NU64 / 4 + 255) / 256, 256, 0, stream>>>(E_u_0, Eu0f, (int)(NU64 / 4));
  fp8_convert<<<(int)(NI64 / 4 + 255) / 256, 256, 0, stream>>>(E_i_0, Ei0f, (int)(NI64 / 4));
  w16_prep<<<(8 * 4096 + 255) / 256, 256, 0, stream>>>(wp, Wt16);

  const int gb = (int)(B64 / 256);  // 1024
  const int sb = (NROW + 3) / 4;    // 25000 blocks, 4 waves each

  for (int l = 0; l < 2; ++l) {
    hipMemsetAsync(Mu, 0, 1024 * 4, stream);  // Mu+Mi contiguous
    svd_reduce2<<<dim3(1024, 2), 256, 0, stream>>>(
        vt, (l == 0) ? E_i_0 : Ei1, ut, (l == 0) ? E_u_0 : Eu1, Mu, Mi);
    SpmmArgs sa;
    sa.Einf[0] = (l == 0) ? Ei0f : Ei1f;  // dir0 gathers items
    sa.Einf[1] = (l == 0) ? Eu0f : Eu1f;  // dir1 gathers users
    sa.Eprev[0] = (l == 0) ? E_u_0 : nullptr;
    sa.Eprev[1] = (l == 0) ? E_i_0 : nullptr;
    sa.Enext[0] = (l == 0) ? Eu1 : nullptr;
    sa.Enext[1] = (l == 0) ? Ei1 : nullptr;
    sa.Enf8[0] = (l == 0) ? Eu1f : nullptr;
    sa.Enf8[1] = (l == 0) ? Ei1f : nullptr;
    sa.Z[0] = Zu; sa.Zd[0] = Zdu;
    sa.Z[1] = Zi; sa.Zd[1] = Zdi;
    sa.nk[0][0] = lk[l][2][0]; sa.nk[0][1] = lk[l][2][1];
    sa.nk[1][0] = lk[l][3][0]; sa.nk[1][1] = lk[l][3][1];
    spmm_row<<<dim3(sb, 2), 256, 0, stream>>>(edgesB, startsAbs, sa, l);
    gather_norm<<<dim3(gb, 3), 256, 0, stream>>>(
        uids, Zu, Zdu, u_mul_s, Mu,
        normbuf16 + (size_t)(0 + l) * B64, normbuf16 + (size_t)(4 + l) * B64,
        normbuf16 + (size_t)(8 + l) * B64);
    gather_norm<<<dim3(gb, 3), 256, 0, stream>>>(
        iids, Zi, Zdi, v_mul_s, Mi,
        normbuf16 + (size_t)(2 + l) * B64, normbuf16 + (size_t)(6 + l) * B64,
        normbuf16 + (size_t)(10 + l) * B64);
  }

  hyper_mfma<<<dim3(C_B / 64, 16), 256, 0, stream>>>(normbuf16, Wt16, hyper16);
  nce_partial<<<dim3(C_B / 128, 4, 16), 256, 0, stream>>>(normbuf16, hyper16,
                                                          rsbuf, psbuf);
  nce_final<<<dim3(C_B / 256, 16), 256, 0, stream>>>(rsbuf, psbuf, slots, nk);
  loss_r_kernel<<<gb, 256, 0, stream>>>(E_u_0, Eu1, Zu, Zdu, E_i_0, Ei1, Zi, Zdi,
                                        uids, pos, neg, slots);
  final_kernel<<<1, 1, 0, stream>>>(slots, out);
}

// Round 15
// 599.614 us; speedup vs baseline: 1.0660x; 1.0563x over previous
//
#include <hip/hip_runtime.h>
#include <hip/hip_bf16.h>
#include <cstdint>

#define C_NU 100000
#define C_NI 100000
#define C_DIM 64
#define C_Q 5
#define C_NE 2000000
#define C_B 4096
#define C_P 10
#define NROW 100000
#define NCB 196      // coarse buckets of 512 rows
#define NCHK 256     // chunks in pass A
#define CHUNK 7813   // ceil(2M/256)

typedef unsigned short u16;
typedef unsigned char u8;
typedef __attribute__((ext_vector_type(8))) short short8;
typedef __attribute__((ext_vector_type(4))) float f32x4;

__device__ static inline int rfl(int v) { return __builtin_amdgcn_readfirstlane(v); }
__device__ static inline uint32_t rflu(uint32_t v) {
  return (uint32_t)__builtin_amdgcn_readfirstlane((int)v);
}

// single-instruction exp2 (exp2f lowers to a slow OCML sequence without fast-math)
__device__ static inline float fast_exp2(float x) {
  float r;
  asm("v_exp_f32 %0, %1" : "=v"(r) : "v"(x));
  return r;
}

// ---------------- Threefry-2x32 (JAX-compatible), 20 rounds ----------------
__host__ __device__ static inline void tf2x32(uint32_t k0, uint32_t k1,
                                              uint32_t& x0, uint32_t& x1) {
  uint32_t k2 = k0 ^ k1 ^ 0x1BD11BDAu;
#define TFR(r) { x0 += x1; x1 = (x1 << r) | (x1 >> (32 - r)); x1 ^= x0; }
  x0 += k0; x1 += k1;
  TFR(13) TFR(15) TFR(26) TFR(6)
  x0 += k1; x1 += k2 + 1u;
  TFR(17) TFR(29) TFR(16) TFR(24)
  x0 += k2; x1 += k0 + 2u;
  TFR(13) TFR(15) TFR(26) TFR(6)
  x0 += k0; x1 += k1 + 3u;
  TFR(17) TFR(29) TFR(16) TFR(24)
  x0 += k1; x1 += k2 + 4u;
  TFR(13) TFR(15) TFR(26) TFR(6)
  x0 += k2; x1 += k0 + 5u;
#undef TFR
}

// partitionable-mode random bits at flat index idx (hi counter = 0)
__device__ static inline float tf_uniform(uint32_t k0, uint32_t k1, uint32_t idx) {
  uint32_t x0 = 0u, x1 = idx;
  tf2x32(k0, k1, x0, x1);
  uint32_t bits = x0 ^ x1;
  return __uint_as_float((bits >> 9) | 0x3F800000u) - 1.0f;
}

__device__ static inline float leaky(float x) { return x >= 0.f ? x : 0.5f * x; }

__device__ static inline u16 f2bf(float f) {  // RNE fp32->bf16
  uint32_t x = __float_as_uint(f);
  return (u16)((x + 0x7FFFu + ((x >> 16) & 1u)) >> 16);
}
__device__ static inline float bf2f(u16 u) {
  return __uint_as_float((uint32_t)u << 16);
}

// fp8 store: byte = sign | 7-bit (4-exp,3-mant) of (x*256), RNE, underflow->0.
__device__ static inline u8 f2fp8(float x) {
  float t = x * 256.f;
  uint32_t sgn = (__float_as_uint(t) >> 24) & 0x80u;
  float a = fabsf(t) * 0x1p-120f;
  uint32_t u = __float_as_uint(a);
  u += 0x7FFFFu + ((u >> 20) & 1u);
  uint32_t mag = u >> 20;
  if (mag > 0x7Fu) mag = 0x7Fu;
  return (u8)(sgn | mag);
}
__device__ static inline float fp8dec(uint32_t b) {  // * 2^-112 folded into weight
  return __uint_as_float(((b & 0x80u) << 24) | ((b & 0x7Fu) << 20));
}

// ---------------- constant maps for the 16 info_nce calls ----------------
// normbuf slots: 0:Zu1 1:Zu2 2:Zi1 3:Zi2 4:Zdu1 5:Zdu2 6:Zdi1 7:Zdi2 8:Gu1 9:Gu2 10:Gi1 11:Gi2
__constant__ int c_gsel[16] = {0,1,2,3, 0,2, 4,5,6,7, 4,6, 0,1,2,3};
__constant__ int c_hsrc[16] = {8,9,10,11, 1,3, 8,9,10,11, 5,7, 4,5,6,7};
// W order: 0:ng0 1:ng1 2:nn 3:dg0 4:dg1 5:dd 6:nd0 7:nd1
__constant__ int c_wsel[16] = {0,1,0,1, 2,2, 3,4,3,4, 5,5, 6,7,6,7};
// slots: 0:n 1:d 2:nn 3:dd 4:nd (5: loss_r sum)
__constant__ int c_slot[16] = {0,0,0,0, 2,2, 1,1,1,1, 3,3, 4,4,4,4};

struct WPtrs { const float* W[8]; };
struct NceKeys { uint32_t k0[16]; uint32_t k1[16]; };
struct DropKeys { uint32_t a[8]; };
struct SpmmArgs {
  const u8* Einf[2];
  const float* Eprev[2];
  float* Enext[2];
  u8* Enf8[2];
  u16* Z[2];
  u16* Zd[2];
  uint32_t nk[2][2];
};

// ---------------- two-level counting sort ----------------

__global__ __launch_bounds__(256) void passA_hist(
    const int* __restrict__ rows, const int* __restrict__ cols,
    uint32_t* __restrict__ cntA) {
  __shared__ uint32_t h[NCB];
  const int dir = blockIdx.y, c = blockIdx.x, t = threadIdx.x;
  for (int i = t; i < NCB; i += 256) h[i] = 0u;
  __syncthreads();
  const int e0 = c * CHUNK, e1 = min(e0 + CHUNK, C_NE);
  const int* ids = dir ? cols : rows;
  for (int e = e0 + t; e < e1; e += 256) atomicAdd(&h[ids[e] >> 9], 1u);
  __syncthreads();
  for (int i = t; i < NCB; i += 256) cntA[(dir * NCB + i) * NCHK + c] = h[i];
}

__global__ __launch_bounds__(512) void scanA1(
    const uint32_t* __restrict__ cntA, uint32_t* __restrict__ offs,
    uint32_t* __restrict__ bsum) {
  __shared__ uint32_t s[512];
  const int b = blockIdx.x, t = threadIdx.x;
  const int idx = b * 512 + t;
  uint32_t v = cntA[idx];
  s[t] = v;
  __syncthreads();
  for (int off = 1; off < 512; off <<= 1) {
    uint32_t a = (t >= off) ? s[t - off] : 0u;
    __syncthreads();
    s[t] += a;
    __syncthreads();
  }
  offs[idx] = s[t] - v;
  if (t == 511) bsum[b] = s[511];
}

__global__ __launch_bounds__(256) void scanA2(
    const uint32_t* __restrict__ bsum, uint32_t* __restrict__ boff) {
  __shared__ uint32_t s[256];
  const int t = threadIdx.x;
  uint32_t v = (t < NCB) ? bsum[t] : 0u;
  s[t] = v;
  __syncthreads();
  for (int off = 1; off < 256; off <<= 1) {
    uint32_t a = (t >= off) ? s[t - off] : 0u;
    __syncthreads();
    s[t] += a;
    __syncthreads();
  }
  if (t < NCB) boff[t] = s[t] - v;
}

__global__ __launch_bounds__(512) void scanA3(
    uint32_t* __restrict__ offs, const uint32_t* __restrict__ boff) {
  offs[blockIdx.x * 512 + threadIdx.x] += boff[blockIdx.x];
}

// record.x = src(17b) | keepL0<<17 | keepL1<<18 | (dst&511)<<19
// record.y = vals[e] * 2^112 (fp8 decode scale pre-folded)
__global__ __launch_bounds__(256) void passA_scatter(
    const int* __restrict__ rows, const int* __restrict__ cols,
    const float* __restrict__ vals, const uint32_t* __restrict__ offs,
    uint2* __restrict__ edgesA, DropKeys dk) {
  __shared__ uint32_t lofs[NCB];
  const int dir = blockIdx.y, c = blockIdx.x, t = threadIdx.x;
  for (int i = t; i < NCB; i += 256) lofs[i] = offs[(dir * NCB + i) * NCHK + c];
  __syncthreads();
  const int e0 = c * CHUNK, e1 = min(e0 + CHUNK, C_NE);
  const uint32_t kA0 = dk.a[dir * 4 + 0], kA1 = dk.a[dir * 4 + 1];
  const uint32_t kB0 = dk.a[dir * 4 + 2], kB1 = dk.a[dir * 4 + 3];
  for (int e = e0 + t; e < e1; e += 256) {
    const int r = rows[e], cc = cols[e];
    const int dst = dir ? cc : r, src = dir ? r : cc;
    const uint32_t kl0 = (tf_uniform(kA0, kA1, (uint32_t)e) < 0.9f) ? 1u : 0u;
    const uint32_t kl1 = (tf_uniform(kB0, kB1, (uint32_t)e) < 0.9f) ? 1u : 0u;
    const uint32_t x = (uint32_t)src | (kl0 << 17) | (kl1 << 18) |
                       ((uint32_t)(dst & 511) << 19);
    const uint32_t pos = atomicAdd(&lofs[dst >> 9], 1u);
    edgesA[pos] = make_uint2(x, __float_as_uint(vals[e] * 0x1p112f));
  }
}

__global__ __launch_bounds__(512) void passB_kernel(
    const uint2* __restrict__ edgesA, const uint32_t* __restrict__ offs,
    uint2* __restrict__ edgesB, uint32_t* __restrict__ starts) {
  __shared__ uint32_t cnt[512];
  __shared__ uint32_t scn[512];
  const int dir = blockIdx.y, cb = blockIdx.x, t = threadIdx.x;
  const uint32_t segStart = offs[(dir * NCB + cb) * NCHK];
  const uint32_t segEnd = (dir == 1 && cb == NCB - 1)
                              ? (uint32_t)(2 * C_NE)
                              : offs[(dir * NCB + cb + 1) * NCHK];
  cnt[t] = 0u;
  __syncthreads();
  for (uint32_t e = segStart + t; e < segEnd; e += 512)
    atomicAdd(&cnt[(edgesA[e].x >> 19) & 511u], 1u);
  __syncthreads();
  uint32_t v = cnt[t];
  scn[t] = v;
  __syncthreads();
  for (int off = 1; off < 512; off <<= 1) {
    uint32_t a = (t >= off) ? scn[t - off] : 0u;
    __syncthreads();
    scn[t] += a;
    __syncthreads();
  }
  const uint32_t rstart = segStart + scn[t] - v;
  const int grow = cb * 512 + t;
  if (grow < NROW) starts[dir * (NROW + 1) + grow] = rstart;
  if (cb == NCB - 1 && t == 0) starts[dir * (NROW + 1) + NROW] = segEnd;
  cnt[t] = rstart;
  __syncthreads();
  for (uint32_t e = segStart + t; e < segEnd; e += 512) {
    const uint2 q = edgesA[e];
    const uint32_t pos = atomicAdd(&cnt[(q.x >> 19) & 511u], 1u);
    edgesB[pos] = q;
  }
}

// ---------------- fp32 -> fp8 table convert ----------------
__global__ __launch_bounds__(256) void fp8_convert(
    const float* __restrict__ src, u8* __restrict__ dst, int n4) {
  int i = blockIdx.x * 256 + threadIdx.x;
  if (i >= n4) return;
  float4 v = ((const float4*)src)[i];
  uint32_t o = (uint32_t)f2fp8(v.x) | ((uint32_t)f2fp8(v.y) << 8) |
               ((uint32_t)f2fp8(v.z) << 16) | ((uint32_t)f2fp8(v.w) << 24);
  ((uint32_t*)dst)[i] = o;
}

// Wt16[w][d][k] = bf16(W[w][k][d])  (pre-transposed for MFMA B-operand)
__global__ __launch_bounds__(256) void w16_prep(WPtrs wp, u16* __restrict__ Wt16) {
  int i = blockIdx.x * 256 + threadIdx.x;
  if (i >= 8 * 4096) return;
  int w = i >> 12, kd = i & 4095, k = kd >> 6, d = kd & 63;
  Wt16[w * 4096 + d * 64 + k] = f2bf(wp.W[w][k * 64 + d]);
}

// ---------------- fused spmm (wave/row, scalarized, fp8, both dirs) ----------------
__global__ __launch_bounds__(256) void spmm_row(
    const uint2* __restrict__ edges, const uint32_t* __restrict__ startsAbs,
    SpmmArgs a, int layer) {
  const int dir = blockIdx.y;
  const int row = rfl(blockIdx.x * 4 + (threadIdx.x >> 6));
  const int lane = threadIdx.x & 63;
  if (row >= NROW) return;
  const uint32_t* starts = startsAbs + dir * (NROW + 1);
  const u8* __restrict__ Einf = a.Einf[dir];
  const uint32_t s0 = rflu(starts[row]);
  const uint32_t s1 = rflu(starts[row + 1]);
  const uint32_t kbit = 1u << (17 + layer);
  float z = 0.f, zd = 0.f;
  uint32_t e = s0;
  for (; e + 8 <= s1; e += 8) {  // 8-deep unroll for gather MLP
    uint32_t p[8], wv[8], b[8];
#pragma unroll
    for (int k = 0; k < 8; ++k) {
      p[k] = rflu(edges[e + k].x);
      wv[k] = rflu(edges[e + k].y);
    }
#pragma unroll
    for (int k = 0; k < 8; ++k)
      b[k] = Einf[(size_t)(p[k] & 0x1FFFFu) * 64 + lane];
#pragma unroll
    for (int k = 0; k < 8; ++k) {
      const float x = fp8dec(b[k]);
      const float v = __uint_as_float(wv[k]);
      z += v * x;
      zd += ((p[k] & kbit) ? v : 0.f) * x;
    }
  }
  for (; e + 4 <= s1; e += 4) {
    const uint32_t p0 = rflu(edges[e].x),     w0 = rflu(edges[e].y);
    const uint32_t p1 = rflu(edges[e + 1].x), w1 = rflu(edges[e + 1].y);
    const uint32_t p2 = rflu(edges[e + 2].x), w2 = rflu(edges[e + 2].y);
    const uint32_t p3 = rflu(edges[e + 3].x), w3 = rflu(edges[e + 3].y);
    const uint32_t b0 = Einf[(size_t)(p0 & 0x1FFFFu) * 64 + lane];
    const uint32_t b1 = Einf[(size_t)(p1 & 0x1FFFFu) * 64 + lane];
    const uint32_t b2 = Einf[(size_t)(p2 & 0x1FFFFu) * 64 + lane];
    const uint32_t b3 = Einf[(size_t)(p3 & 0x1FFFFu) * 64 + lane];
    const float x0 = fp8dec(b0), x1 = fp8dec(b1);
    const float x2 = fp8dec(b2), x3 = fp8dec(b3);
    const float v0 = __uint_as_float(w0), v1 = __uint_as_float(w1);
    const float v2 = __uint_as_float(w2), v3 = __uint_as_float(w3);
    const float d0 = (p0 & kbit) ? v0 : 0.f;
    const float d1 = (p1 & kbit) ? v1 : 0.f;
    const float d2 = (p2 & kbit) ? v2 : 0.f;
    const float d3 = (p3 & kbit) ? v3 : 0.f;
    z += v0 * x0; zd += d0 * x0;
    z += v1 * x1; zd += d1 * x1;
    z += v2 * x2; zd += d2 * x2;
    z += v3 * x3; zd += d3 * x3;
  }
  for (; e < s1; ++e) {
    const uint32_t p = rflu(edges[e].x), wv = rflu(edges[e].y);
    const float x = fp8dec(Einf[(size_t)(p & 0x1FFFFu) * 64 + lane]);
    const float v = __uint_as_float(wv);
    z += v * x;
    zd += ((p & kbit) ? v : 0.f) * x;
  }
  z = leaky(z);
  zd = leaky(zd * (1.0f / 0.9f));
  // noise-augmented view
  const float u = tf_uniform(a.nk[dir][0], a.nk[dir][1],
                             (uint32_t)row * 64u + (uint32_t)lane);
  float ss = u * u;
#pragma unroll
  for (int off = 1; off < 64; off <<= 1) ss += __shfl_xor(ss, off);
  const float nrm = fmaxf(sqrtf(ss), 1e-12f);
  const float sg = (z > 0.f) ? 1.f : (z < 0.f ? -1.f : 0.f);
  z += sg * (u / nrm) * 0.1f;
  const size_t j = (size_t)row * 64 + lane;
  a.Z[dir][j] = f2bf(z);
  a.Zd[dir][j] = f2bf(zd);
  if (a.Enext[dir]) {  // layer 0 only
    const float en = z + zd + a.Eprev[dir][j];
    a.Enext[dir][j] = en;
    a.Enf8[dir][j] = f2fp8(en);
  }
}

// ---------------- dual-dir SVD middle matrix, block-reduced atomics ----------------
__global__ __launch_bounds__(256) void svd_reduce2(
    const float* __restrict__ T0, const float* __restrict__ E0,
    const float* __restrict__ T1, const float* __restrict__ E1,
    float* __restrict__ Mu, float* __restrict__ Mi) {
  const int dir = blockIdx.y;
  const float* __restrict__ T = dir ? T1 : T0;
  const float* __restrict__ E = dir ? E1 : E0;
  float* __restrict__ M = dir ? Mi : Mu;
  const int lane = threadIdx.x & 63;
  const int wl = threadIdx.x >> 6;
  const int gw = blockIdx.x * 4 + wl;
  float a0 = 0.f, a1 = 0.f, a2 = 0.f, a3 = 0.f, a4 = 0.f;
  for (int i = gw; i < NROW; i += 4096) {
    const float x = E[(size_t)i * 64 + lane];
    a0 += T[i] * x;
    a1 += T[NROW + i] * x;
    a2 += T[2 * NROW + i] * x;
    a3 += T[3 * NROW + i] * x;
    a4 += T[4 * NROW + i] * x;
  }
  __shared__ float red[4][5][64];
  red[wl][0][lane] = a0; red[wl][1][lane] = a1; red[wl][2][lane] = a2;
  red[wl][3][lane] = a3; red[wl][4][lane] = a4;
  __syncthreads();
  for (int o = threadIdx.x; o < 320; o += 256) {
    const int q = o >> 6, d = o & 63;
    const float s = red[0][q][d] + red[1][q][d] + red[2][q][d] + red[3][q][d];
    atomicAdd(&M[o], s);
  }
}

// gather batch rows & L2-normalize -> bf16; blockIdx.y selects {Z, Zd, G}
__global__ __launch_bounds__(256) void gather_norm(
    const int* __restrict__ ids, const u16* __restrict__ Z,
    const u16* __restrict__ Zd, const float* __restrict__ mul_s,
    const float* __restrict__ M, u16* __restrict__ oZ,
    u16* __restrict__ oZd, u16* __restrict__ oG) {
  long long t = (long long)blockIdx.x * blockDim.x + threadIdx.x;
  int b = (int)(t >> 6);
  int d = (int)(t & 63);
  if (b >= C_B) return;
  int id = rfl(ids[b]);
  float v;
  u16* out;
  if (blockIdx.y == 0) { v = bf2f(Z[(size_t)id * 64 + d]); out = oZ; }
  else if (blockIdx.y == 1) { v = bf2f(Zd[(size_t)id * 64 + d]); out = oZd; }
  else {
    float s = 0.f;
#pragma unroll
    for (int q = 0; q < 5; ++q) s += mul_s[(size_t)id * 5 + q] * M[q * 64 + d];
    v = leaky(s);
    out = oG;
  }
  float ss = v * v;
#pragma unroll
  for (int off = 1; off < 64; off <<= 1) ss += __shfl_xor(ss, off);
  float nrm = fmaxf(sqrtf(ss), 1e-12f);
  out[(size_t)b * 64 + d] = f2bf(v / nrm);
}

// ---------------- MFMA hyper (LDS-free): hy = (X @ W) * log2e/TEMP ----------------
__global__ __launch_bounds__(256) void hyper_mfma(
    const u16* __restrict__ nb, const u16* __restrict__ Wt16,
    u16* __restrict__ hy) {
  const int call = blockIdx.y;
  const int b0 = blockIdx.x * 64;
  const int lane = threadIdx.x & 63, wid = threadIdx.x >> 6;
  const u16* X = nb + (size_t)c_hsrc[call] * C_B * 64;
  const u16* Wt = Wt16 + (size_t)c_wsel[call] * 4096;
  const int am = (wid << 4) + (lane & 15);
  const int ke = ((lane >> 4) << 3);  // fragment k-offset (elements)
  short8 af[2];
#pragma unroll
  for (int ks = 0; ks < 2; ++ks)
    af[ks] = *(const short8*)&X[(size_t)(b0 + am) * 64 + ks * 32 + ke];
  const int ob = b0 + (wid << 4) + ((lane >> 4) << 2);
#pragma unroll
  for (int n = 0; n < 4; ++n) {
    const int bn = (n << 4) + (lane & 15);
    f32x4 acc = {0.f, 0.f, 0.f, 0.f};
#pragma unroll
    for (int ks = 0; ks < 2; ++ks) {
      short8 bf = *(const short8*)&Wt[(size_t)bn * 64 + ks * 32 + ke];
      acc = __builtin_amdgcn_mfma_f32_16x16x32_bf16(af[ks], bf, acc, 0, 0, 0);
    }
    const int d = (n << 4) + (lane & 15);
#pragma unroll
    for (int j = 0; j < 4; ++j)
      hy[(size_t)call * C_B * 64 + (size_t)(ob + j) * 64 + d] =
          f2bf(acc[j] * 7.2134752f);  // fold log2(e)/TEMP into H
  }
}

// ---------------- MFMA info_nce partials: 128 g-rows x 16 H-tiles per block ----
// grid: (32 g-tiles, 4 jt-chunks, 16 calls); G fragments loaded direct from global
__global__ __launch_bounds__(256) void nce_partial(
    const u16* __restrict__ nb, const u16* __restrict__ hy,
    float* __restrict__ rsbuf, float* __restrict__ psbuf) {
  const int call = blockIdx.z;
  const int jc = blockIdx.y;
  const u16* G = nb + (size_t)c_gsel[call] * C_B * 64;
  const u16* H = hy + (size_t)call * C_B * 64;
  const int br = blockIdx.x * 128;
  const int jt0 = jc * 16;
  __shared__ u16 Hs[2][64 * 64];
  const int tid = threadIdx.x, lane = tid & 63, wid = tid >> 6;
  const int ke = ((lane >> 4) << 3);
  short8 bfG[2][2];
#pragma unroll
  for (int s = 0; s < 2; ++s)
#pragma unroll
    for (int ks = 0; ks < 2; ++ks) {
      const int gc = (wid << 5) + (s << 4) + (lane & 15);
      bfG[s][ks] = *(const short8*)&G[(size_t)(br + gc) * 64 + ks * 32 + ke];
    }
  const int r = tid >> 2, seg = tid & 3;
  const int base = r * 128 + seg * 32, sw = (r & 7) << 4;
  {
    const uint4* src = (const uint4*)&H[(size_t)(jt0 * 64 + r) * 64 + seg * 16];
    uint4 a = src[0], b = src[1];
    *(uint4*)((char*)Hs[0] + (base ^ sw)) = a;
    *(uint4*)((char*)Hs[0] + ((base + 16) ^ sw)) = b;
  }
  float rs[2] = {0.f, 0.f}, ps[2] = {0.f, 0.f};
  const int jt_diag = (blockIdx.x << 1) + (wid >> 1);
  const int hsd0 = (wid & 1) << 1;
  int cur = 0;
  for (int jt = jt0; jt < jt0 + 16; ++jt) {
    __syncthreads();  // Hs[cur] ready
    uint4 na, nb_;
    if (jt + 1 < jt0 + 16) {  // prefetch next H tile
      const uint4* src = (const uint4*)&H[(size_t)((jt + 1) * 64 + r) * 64 + seg * 16];
      na = src[0]; nb_ = src[1];
    }
    const bool dj = (jt == jt_diag);
    const char* Hb = (const char*)(Hs[cur]);
#pragma unroll
    for (int hs = 0; hs < 4; ++hs) {
      const int hr = (hs << 4) + (lane & 15);
      const int offA0 = (hr * 128 + ((lane >> 4) << 4)) ^ ((hr & 7) << 4);
      const int offA1 = (hr * 128 + 64 + ((lane >> 4) << 4)) ^ ((hr & 7) << 4);
      const short8 af0 = *(const short8*)(Hb + offA0);
      const short8 af1 = *(const short8*)(Hb + offA1);
      f32x4 acc0 = {0.f, 0.f, 0.f, 0.f}, acc1 = {0.f, 0.f, 0.f, 0.f};
      __builtin_amdgcn_s_setprio(1);
      acc0 = __builtin_amdgcn_mfma_f32_16x16x32_bf16(af0, bfG[0][0], acc0, 0, 0, 0);
      acc0 = __builtin_amdgcn_mfma_f32_16x16x32_bf16(af1, bfG[0][1], acc0, 0, 0, 0);
      acc1 = __builtin_amdgcn_mfma_f32_16x16x32_bf16(af0, bfG[1][0], acc1, 0, 0, 0);
      acc1 = __builtin_amdgcn_mfma_f32_16x16x32_bf16(af1, bfG[1][1], acc1, 0, 0, 0);
      __builtin_amdgcn_s_setprio(0);
      float e0[4], e1[4];
#pragma unroll
      for (int j = 0; j < 4; ++j) {
        e0[j] = fast_exp2(acc0[j]);  // H pre-scaled by log2e/TEMP
        e1[j] = fast_exp2(acc1[j]);
      }
      rs[0] += (e0[0] + e0[1]) + (e0[2] + e0[3]);
      rs[1] += (e1[0] + e1[1]) + (e1[2] + e1[3]);
      if (dj) {
        const int jm = (lane & 15) - ((lane >> 4) << 2);
        if (hs == hsd0) {
#pragma unroll
          for (int j = 0; j < 4; ++j)
            if (jm == j) ps[0] = e0[j];
        }
        if (hs == hsd0 + 1) {
#pragma unroll
          for (int j = 0; j < 4; ++j)
            if (jm == j) ps[1] = e1[j];
        }
      }
    }
    if (jt + 1 < jt0 + 16) {
      *(uint4*)((char*)Hs[cur ^ 1] + (base ^ sw)) = na;
      *(uint4*)((char*)Hs[cur ^ 1] + ((base + 16) ^ sw)) = nb_;
    }
    cur ^= 1;
  }
#pragma unroll
  for (int s = 0; s < 2; ++s) {
    rs[s] += __shfl_xor(rs[s], 16); rs[s] += __shfl_xor(rs[s], 32);
    ps[s] += __shfl_xor(ps[s], 16); ps[s] += __shfl_xor(ps[s], 32);
  }
  if ((lane >> 4) == 0) {
    const bool own_diag = ((jt_diag >> 4) == jc);  // wave-uniform
#pragma unroll
    for (int s = 0; s < 2; ++s) {
      const int gg = br + (wid << 5) + (s << 4) + (lane & 15);
      atomicAdd(&rsbuf[(size_t)call * C_B + gg], rs[s]);
      if (own_diag) psbuf[(size_t)call * C_B + gg] = ps[s];
    }
  }
}

// finalize: v = -log(ps/(rs+eps)+eps), mask, reduce to slots
__global__ __launch_bounds__(256) void nce_final(
    const float* __restrict__ rsbuf, const float* __restrict__ psbuf,
    float* __restrict__ slots, NceKeys nk) {
  const int call = blockIdx.y;
  const int g = blockIdx.x * 256 + threadIdx.x;
  const float rs = rsbuf[(size_t)call * C_B + g];
  const float ps = psbuf[(size_t)call * C_B + g];
  const float v = -__logf(ps / (rs + 1e-8f) + 1e-8f);
  const float u = tf_uniform(nk.k0[call], nk.k1[call], (uint32_t)g);
  float c = (u > 0.5f) ? v : 0.f;
#pragma unroll
  for (int off = 1; off < 64; off <<= 1) c += __shfl_xor(c, off);
  __shared__ float wsum[4];
  if ((threadIdx.x & 63) == 0) wsum[threadIdx.x >> 6] = c;
  __syncthreads();
  if (threadIdx.x == 0)
    atomicAdd(&slots[c_slot[call]], wsum[0] + wsum[1] + wsum[2] + wsum[3]);
}

// E_sum = E0 + 2*E1 + Z2 + Zd2  (E2 never materialized; Z in bf16)
__global__ __launch_bounds__(256) void loss_r_kernel(
    const float* __restrict__ E0u, const float* __restrict__ Eu1,
    const u16* __restrict__ Zu, const u16* __restrict__ Zdu,
    const float* __restrict__ E0i, const float* __restrict__ Ei1,
    const u16* __restrict__ Zi, const u16* __restrict__ Zdi,
    const int* __restrict__ uids, const int* __restrict__ pos,
    const int* __restrict__ neg, float* __restrict__ slots) {
  long long t = (long long)blockIdx.x * blockDim.x + threadIdx.x;
  int b = (int)(t >> 6);
  int d = (int)(t & 63);
  if (b >= C_B) return;
  size_t ju = (size_t)rfl(uids[b]) * 64 + d;
  float u = E0u[ju] + 2.f * Eu1[ju] + bf2f(Zu[ju]) + bf2f(Zdu[ju]);
  float bpr = 0.f, pmin = 3.4e38f, nmax = -3.4e38f;
  for (int p = 0; p < C_P; ++p) {
    size_t jp = (size_t)rfl(pos[b * C_P + p]) * 64 + d;
    size_t jn = (size_t)rfl(neg[b * C_P + p]) * 64 + d;
    float pe = E0i[jp] + 2.f * Ei1[jp] + bf2f(Zi[jp]) + bf2f(Zdi[jp]);
    float ne = E0i[jn] + 2.f * Ei1[jn] + bf2f(Zi[jn]) + bf2f(Zdi[jn]);
    float psc = u * pe, nsc = u * ne;
#pragma unroll
    for (int off = 1; off < 64; off <<= 1) {
      psc += __shfl_xor(psc, off);
      nsc += __shfl_xor(nsc, off);
    }
    pmin = fminf(pmin, psc);
    nmax = fmaxf(nmax, nsc);
    bpr += fmaxf(1.f - psc + nsc, 0.f);
  }
  if (d == 0) {
    float hd = (nmax - pmin > 0.005f) ? 10.f * (nmax - pmin) : 0.f;
    atomicAdd(&slots[5], bpr + hd);
  }
}

__global__ void final_kernel(const float* __restrict__ slots, float* __restrict__ out) {
  if (threadIdx.x == 0 && blockIdx.x == 0) {
    float n = slots[0], dl = slots[1], nn = slots[2], dd = slots[3], nd = slots[4];
    float lr = slots[5] / (float)C_B;
    out[0] = lr + 0.2f * (n + dl) + 0.2f * (nn + dd + nd);
    out[1] = lr;
    out[2] = dl;
    out[3] = n;
  }
}

// ---------------- host ----------------
extern "C" void kernel_launch(void* const* d_in, const int* in_sizes, int n_in,
                              void* d_out, int out_size, void* d_ws, size_t ws_size,
                              hipStream_t stream) {
  (void)in_sizes; (void)n_in; (void)out_size;
  const float* E_u_0   = (const float*)d_in[0];
  const float* E_i_0   = (const float*)d_in[1];
  const float* adjvals = (const float*)d_in[2];
  const float* u_mul_s = (const float*)d_in[3];
  const float* v_mul_s = (const float*)d_in[4];
  const float* ut      = (const float*)d_in[5];
  const float* vt      = (const float*)d_in[6];
  const float* W_nn    = (const float*)d_in[7];
  const float* W_dd    = (const float*)d_in[8];
  const float* W_ng    = (const float*)d_in[9];
  const float* W_dg    = (const float*)d_in[10];
  const float* W_nd    = (const float*)d_in[11];
  const int* adj_rows  = (const int*)d_in[12];
  const int* adj_cols  = (const int*)d_in[13];
  const int* uids      = (const int*)d_in[14];
  const int* iids      = (const int*)d_in[15];
  const int* pos       = (const int*)d_in[16];
  const int* neg       = (const int*)d_in[17];
  float* out = (float*)d_out;

  const size_t NU64 = (size_t)C_NU * 64;
  const size_t NI64 = (size_t)C_NI * 64;
  const size_t B64  = (size_t)C_B * 64;

  float* w = (float*)d_ws;
  float* Eu1 = w; w += NU64;
  float* Ei1 = w; w += NI64;
  u16* Zu  = (u16*)w;            // 4 contiguous bf16 Z buffers; edgesA aliases
  u16* Zdu = Zu + NU64;
  u16* Zi  = Zdu + NU64;
  u16* Zdi = Zi + NI64;
  w += 2 * NU64;                 // 4 * NU64 u16 = 2 * NU64 floats
  float* Mu = w; w += 512;
  float* Mi = w; w += 512;
  u16* normbuf16 = (u16*)w; w += 6 * B64;     // 12 bf16 buffers of B64
  float* slots = w; w += 16;
  uint2* edgesB = (uint2*)w; w += 4 * C_NE;   // 32 MB final CSR (both dirs)
  u16* hyper16 = (u16*)edgesB;                // alias: edgesB dead before hyper
  u16* Wt16 = (u16*)w; w += 16384;
  uint32_t* cntA = (uint32_t*)w; w += NCB * NCHK * 2;
  uint32_t* offs = (uint32_t*)w; w += NCB * NCHK * 2;
  uint32_t* bsumA = (uint32_t*)w; w += NCB;
  uint32_t* boffA = (uint32_t*)w; w += NCB;
  uint32_t* startsAbs = (uint32_t*)w; w += 2 * (NROW + 1);
  u8* Eu0f = (u8*)w; w += NU64 / 4;           // fp8 gather tables
  u8* Ei0f = (u8*)w; w += NI64 / 4;
  u8* Eu1f = (u8*)w; w += NU64 / 4;
  u8* Ei1f = (u8*)w; w += NI64 / 4;           // OWN storage (no alias: G16 race fix)
  float* rsbuf = w; w += 16 * C_B;            // nce partial denominators
  float* psbuf = w; w += 16 * C_B;            // nce diag numerators
  uint2* edgesA = (uint2*)Zu;                 // 32 MB coarse buffer (< Zu..Zi)
  if ((size_t)((char*)w - (char*)d_ws) > ws_size) return;

  // ---- host-side JAX key derivation (partitionable threefry) ----
  auto ksplit = [](uint32_t a, uint32_t b, uint32_t idx, uint32_t& o0, uint32_t& o1) {
    uint32_t x0 = 0u, x1 = idx;
    tf2x32(a, b, x0, x1);
    o0 = x0; o1 = x1;
  };
  uint32_t rk0 = 0u, rk1 = 42u;
  uint32_t lk[2][4][2];
  for (int l = 0; l < 2; ++l) {
    uint32_t n0, n1;
    ksplit(rk0, rk1, 0u, n0, n1);
    for (int i = 0; i < 4; ++i) ksplit(rk0, rk1, (uint32_t)(i + 1), lk[l][i][0], lk[l][i][1]);
    rk0 = n0; rk1 = n1;
  }
  NceKeys nk;
  {
    uint32_t mk0 = 0u, mk1 = 7u;
    for (int i = 0; i < 16; ++i) {
      uint32_t n0, n1;
      ksplit(mk0, mk1, 0u, n0, n1);
      ksplit(mk0, mk1, 1u, nk.k0[i], nk.k1[i]);
      mk0 = n0; mk1 = n1;
    }
  }
  DropKeys dk;
  dk.a[0] = lk[0][0][0]; dk.a[1] = lk[0][0][1];
  dk.a[2] = lk[1][0][0]; dk.a[3] = lk[1][0][1];
  dk.a[4] = lk[0][1][0]; dk.a[5] = lk[0][1][1];
  dk.a[6] = lk[1][1][0]; dk.a[7] = lk[1][1][1];
  WPtrs wp;
  wp.W[0] = W_ng; wp.W[1] = W_ng + 4096;
  wp.W[2] = W_nn;
  wp.W[3] = W_dg; wp.W[4] = W_dg + 4096;
  wp.W[5] = W_dd;
  wp.W[6] = W_nd; wp.W[7] = W_nd + 4096;

  // ---- sort + preps ----
  hipMemsetAsync(slots, 0, 16 * 4, stream);
  hipMemsetAsync(rsbuf, 0, 16 * C_B * 4, stream);
  passA_hist<<<dim3(NCHK, 2), 256, 0, stream>>>(adj_rows, adj_cols, cntA);
  scanA1<<<NCB, 512, 0, stream>>>(cntA, offs, bsumA);
  scanA2<<<1, 256, 0, stream>>>(bsumA, boffA);
  scanA3<<<NCB, 512, 0, stream>>>(offs, boffA);
  passA_scatter<<<dim3(NCHK, 2), 256, 0, stream>>>(
      adj_rows, adj_cols, adjvals, offs, edgesA, dk);
  passB_kernel<<<dim3(NCB, 2), 512, 0, stream>>>(edgesA, offs, edgesB, startsAbs);
  fp8_convert<<<(int)(NU64 / 4 + 255) / 256, 256, 0, stream>>>(E_u_0, Eu0f, (int)(NU64 / 4));
  fp8_convert<<<(int)(NI64 / 4 + 255) / 256, 256, 0, stream>>>(E_i_0, Ei0f, (int)(NI64 / 4));
  w16_prep<<<(8 * 4096 + 255) / 256, 256, 0, stream>>>(wp, Wt16);

  const int gb = (int)(B64 / 256);  // 1024
  const int sb = (NROW + 3) / 4;    // 25000 blocks, 4 waves each

  for (int l = 0; l < 2; ++l) {
    hipMemsetAsync(Mu, 0, 1024 * 4, stream);  // Mu+Mi contiguous
    svd_reduce2<<<dim3(1024, 2), 256, 0, stream>>>(
        vt, (l == 0) ? E_i_0 : Ei1, ut, (l == 0) ? E_u_0 : Eu1, Mu, Mi);
    SpmmArgs sa;
    sa.Einf[0] = (l == 0) ? Ei0f : Ei1f;  // dir0 gathers items
    sa.Einf[1] = (l == 0) ? Eu0f : Eu1f;  // dir1 gathers users
    sa.Eprev[0] = (l == 0) ? E_u_0 : nullptr;
    sa.Eprev[1] = (l == 0) ? E_i_0 : nullptr;
    sa.Enext[0] = (l == 0) ? Eu1 : nullptr;
    sa.Enext[1] = (l == 0) ? Ei1 : nullptr;
    sa.Enf8[0] = (l == 0) ? Eu1f : nullptr;
    sa.Enf8[1] = (l == 0) ? Ei1f : nullptr;
    sa.Z[0] = Zu; sa.Zd[0] = Zdu;
    sa.Z[1] = Zi; sa.Zd[1] = Zdi;
    sa.nk[0][0] = lk[l][2][0]; sa.nk[0][1] = lk[l][2][1];
    sa.nk[1][0] = lk[l][3][0]; sa.nk[1][1] = lk[l][3][1];
    spmm_row<<<dim3(sb, 2), 256, 0, stream>>>(edgesB, startsAbs, sa, l);
    gather_norm<<<dim3(gb, 3), 256, 0, stream>>>(
        uids, Zu, Zdu, u_mul_s, Mu,
        normbuf16 + (size_t)(0 + l) * B64, normbuf16 + (size_t)(4 + l) * B64,
        normbuf16 + (size_t)(8 + l) * B64);
    gather_norm<<<dim3(gb, 3), 256, 0, stream>>>(
        iids, Zi, Zdi, v_mul_s, Mi,
        normbuf16 + (size_t)(2 + l) * B64, normbuf16 + (size_t)(6 + l) * B64,
        normbuf16 + (size_t)(10 + l) * B64);
  }

  hyper_mfma<<<dim3(C_B / 64, 16), 256, 0, stream>>>(normbuf16, Wt16, hyper16);
  nce_partial<<<dim3(C_B / 128, 4, 16), 256, 0, stream>>>(normbuf16, hyper16,
                                                          rsbuf, psbuf);
  nce_final<<<dim3(C_B / 256, 16), 256, 0, stream>>>(rsbuf, psbuf, slots, nk);
  loss_r_kernel<<<gb, 256, 0, stream>>>(E_u_0, Eu1, Zu, Zdu, E_i_0, Ei1, Zi, Zdi,
                                        uids, pos, neg, slots);
  final_kernel<<<1, 1, 0, stream>>>(slots, out);
}

// Round 16
// 574.255 us; speedup vs baseline: 1.1131x; 1.0442x over previous
//
#include <hip/hip_runtime.h>
#include <hip/hip_bf16.h>
#include <cstdint>

#define C_NU 100000
#define C_NI 100000
#define C_DIM 64
#define C_Q 5
#define C_NE 2000000
#define C_B 4096
#define C_P 10
#define NROW 100000
#define NCB 196      // coarse buckets of 512 rows
#define NCHK 256     // chunks in pass A
#define CHUNK 7813   // ceil(2M/256)

typedef unsigned short u16;
typedef unsigned char u8;
typedef __attribute__((ext_vector_type(8))) short short8;
typedef __attribute__((ext_vector_type(4))) float f32x4;

__device__ static inline int rfl(int v) { return __builtin_amdgcn_readfirstlane(v); }
__device__ static inline uint32_t rflu(uint32_t v) {
  return (uint32_t)__builtin_amdgcn_readfirstlane((int)v);
}

// single-instruction exp2 (exp2f lowers to a slow OCML sequence without fast-math)
__device__ static inline float fast_exp2(float x) {
  float r;
  asm("v_exp_f32 %0, %1" : "=v"(r) : "v"(x));
  return r;
}

// ---------------- Threefry-2x32 (JAX-compatible), 20 rounds ----------------
__host__ __device__ static inline void tf2x32(uint32_t k0, uint32_t k1,
                                              uint32_t& x0, uint32_t& x1) {
  uint32_t k2 = k0 ^ k1 ^ 0x1BD11BDAu;
#define TFR(r) { x0 += x1; x1 = (x1 << r) | (x1 >> (32 - r)); x1 ^= x0; }
  x0 += k0; x1 += k1;
  TFR(13) TFR(15) TFR(26) TFR(6)
  x0 += k1; x1 += k2 + 1u;
  TFR(17) TFR(29) TFR(16) TFR(24)
  x0 += k2; x1 += k0 + 2u;
  TFR(13) TFR(15) TFR(26) TFR(6)
  x0 += k0; x1 += k1 + 3u;
  TFR(17) TFR(29) TFR(16) TFR(24)
  x0 += k1; x1 += k2 + 4u;
  TFR(13) TFR(15) TFR(26) TFR(6)
  x0 += k2; x1 += k0 + 5u;
#undef TFR
}

// partitionable-mode random bits at flat index idx (hi counter = 0)
__device__ static inline float tf_uniform(uint32_t k0, uint32_t k1, uint32_t idx) {
  uint32_t x0 = 0u, x1 = idx;
  tf2x32(k0, k1, x0, x1);
  uint32_t bits = x0 ^ x1;
  return __uint_as_float((bits >> 9) | 0x3F800000u) - 1.0f;
}

__device__ static inline float leaky(float x) { return x >= 0.f ? x : 0.5f * x; }

__device__ static inline u16 f2bf(float f) {  // RNE fp32->bf16
  uint32_t x = __float_as_uint(f);
  return (u16)((x + 0x7FFFu + ((x >> 16) & 1u)) >> 16);
}
__device__ static inline float bf2f(u16 u) {
  return __uint_as_float((uint32_t)u << 16);
}

// fp8 store: byte = sign | 7-bit (4-exp,3-mant) of (x*256), RNE, underflow->0.
__device__ static inline u8 f2fp8(float x) {
  float t = x * 256.f;
  uint32_t sgn = (__float_as_uint(t) >> 24) & 0x80u;
  float a = fabsf(t) * 0x1p-120f;
  uint32_t u = __float_as_uint(a);
  u += 0x7FFFFu + ((u >> 20) & 1u);
  uint32_t mag = u >> 20;
  if (mag > 0x7Fu) mag = 0x7Fu;
  return (u8)(sgn | mag);
}
__device__ static inline float fp8dec(uint32_t b) {  // * 2^-112 folded into weight
  return __uint_as_float(((b & 0x80u) << 24) | ((b & 0x7Fu) << 20));
}

// ---------------- constant maps for the 16 info_nce calls ----------------
// normbuf slots: 0:Zu1 1:Zu2 2:Zi1 3:Zi2 4:Zdu1 5:Zdu2 6:Zdi1 7:Zdi2 8:Gu1 9:Gu2 10:Gi1 11:Gi2
__constant__ int c_gsel[16] = {0,1,2,3, 0,2, 4,5,6,7, 4,6, 0,1,2,3};
__constant__ int c_hsrc[16] = {8,9,10,11, 1,3, 8,9,10,11, 5,7, 4,5,6,7};
// W order: 0:ng0 1:ng1 2:nn 3:dg0 4:dg1 5:dd 6:nd0 7:nd1
__constant__ int c_wsel[16] = {0,1,0,1, 2,2, 3,4,3,4, 5,5, 6,7,6,7};
// slots: 0:n 1:d 2:nn 3:dd 4:nd (5: loss_r sum)
__constant__ int c_slot[16] = {0,0,0,0, 2,2, 1,1,1,1, 3,3, 4,4,4,4};

struct WPtrs { const float* W[8]; };
struct NceKeys { uint32_t k0[16]; uint32_t k1[16]; };
struct DropKeys { uint32_t a[8]; };
struct SpmmArgs {
  const u8* Einf[2];
  const float* Eprev[2];
  float* Enext[2];
  u8* Enf8[2];
  u16* Z[2];
  u16* Zd[2];
  uint32_t nk[2][2];
};

// ---------------- two-level counting sort ----------------

__global__ __launch_bounds__(256) void passA_hist(
    const int* __restrict__ rows, const int* __restrict__ cols,
    uint32_t* __restrict__ cntA) {
  __shared__ uint32_t h[NCB];
  const int dir = blockIdx.y, c = blockIdx.x, t = threadIdx.x;
  for (int i = t; i < NCB; i += 256) h[i] = 0u;
  __syncthreads();
  const int e0 = c * CHUNK, e1 = min(e0 + CHUNK, C_NE);
  const int* ids = dir ? cols : rows;
  for (int e = e0 + t; e < e1; e += 256) atomicAdd(&h[ids[e] >> 9], 1u);
  __syncthreads();
  for (int i = t; i < NCB; i += 256) cntA[(dir * NCB + i) * NCHK + c] = h[i];
}

__global__ __launch_bounds__(512) void scanA1(
    const uint32_t* __restrict__ cntA, uint32_t* __restrict__ offs,
    uint32_t* __restrict__ bsum) {
  __shared__ uint32_t s[512];
  const int b = blockIdx.x, t = threadIdx.x;
  const int idx = b * 512 + t;
  uint32_t v = cntA[idx];
  s[t] = v;
  __syncthreads();
  for (int off = 1; off < 512; off <<= 1) {
    uint32_t a = (t >= off) ? s[t - off] : 0u;
    __syncthreads();
    s[t] += a;
    __syncthreads();
  }
  offs[idx] = s[t] - v;
  if (t == 511) bsum[b] = s[511];
}

__global__ __launch_bounds__(256) void scanA2(
    const uint32_t* __restrict__ bsum, uint32_t* __restrict__ boff) {
  __shared__ uint32_t s[256];
  const int t = threadIdx.x;
  uint32_t v = (t < NCB) ? bsum[t] : 0u;
  s[t] = v;
  __syncthreads();
  for (int off = 1; off < 256; off <<= 1) {
    uint32_t a = (t >= off) ? s[t - off] : 0u;
    __syncthreads();
    s[t] += a;
    __syncthreads();
  }
  if (t < NCB) boff[t] = s[t] - v;
}

__global__ __launch_bounds__(512) void scanA3(
    uint32_t* __restrict__ offs, const uint32_t* __restrict__ boff) {
  offs[blockIdx.x * 512 + threadIdx.x] += boff[blockIdx.x];
}

// record.x = src(17b) | keepL0<<17 | keepL1<<18 | (dst&511)<<19
// record.y = vals[e] * 2^112 (fp8 decode scale pre-folded)
__global__ __launch_bounds__(256) void passA_scatter(
    const int* __restrict__ rows, const int* __restrict__ cols,
    const float* __restrict__ vals, const uint32_t* __restrict__ offs,
    uint2* __restrict__ edgesA, DropKeys dk) {
  __shared__ uint32_t lofs[NCB];
  const int dir = blockIdx.y, c = blockIdx.x, t = threadIdx.x;
  for (int i = t; i < NCB; i += 256) lofs[i] = offs[(dir * NCB + i) * NCHK + c];
  __syncthreads();
  const int e0 = c * CHUNK, e1 = min(e0 + CHUNK, C_NE);
  const uint32_t kA0 = dk.a[dir * 4 + 0], kA1 = dk.a[dir * 4 + 1];
  const uint32_t kB0 = dk.a[dir * 4 + 2], kB1 = dk.a[dir * 4 + 3];
  for (int e = e0 + t; e < e1; e += 256) {
    const int r = rows[e], cc = cols[e];
    const int dst = dir ? cc : r, src = dir ? r : cc;
    const uint32_t kl0 = (tf_uniform(kA0, kA1, (uint32_t)e) < 0.9f) ? 1u : 0u;
    const uint32_t kl1 = (tf_uniform(kB0, kB1, (uint32_t)e) < 0.9f) ? 1u : 0u;
    const uint32_t x = (uint32_t)src | (kl0 << 17) | (kl1 << 18) |
                       ((uint32_t)(dst & 511) << 19);
    const uint32_t pos = atomicAdd(&lofs[dst >> 9], 1u);
    edgesA[pos] = make_uint2(x, __float_as_uint(vals[e] * 0x1p112f));
  }
}

__global__ __launch_bounds__(512) void passB_kernel(
    const uint2* __restrict__ edgesA, const uint32_t* __restrict__ offs,
    uint2* __restrict__ edgesB, uint32_t* __restrict__ starts) {
  __shared__ uint32_t cnt[512];
  __shared__ uint32_t scn[512];
  const int dir = blockIdx.y, cb = blockIdx.x, t = threadIdx.x;
  const uint32_t segStart = offs[(dir * NCB + cb) * NCHK];
  const uint32_t segEnd = (dir == 1 && cb == NCB - 1)
                              ? (uint32_t)(2 * C_NE)
                              : offs[(dir * NCB + cb + 1) * NCHK];
  cnt[t] = 0u;
  __syncthreads();
  for (uint32_t e = segStart + t; e < segEnd; e += 512)
    atomicAdd(&cnt[(edgesA[e].x >> 19) & 511u], 1u);
  __syncthreads();
  uint32_t v = cnt[t];
  scn[t] = v;
  __syncthreads();
  for (int off = 1; off < 512; off <<= 1) {
    uint32_t a = (t >= off) ? scn[t - off] : 0u;
    __syncthreads();
    scn[t] += a;
    __syncthreads();
  }
  const uint32_t rstart = segStart + scn[t] - v;
  const int grow = cb * 512 + t;
  if (grow < NROW) starts[dir * (NROW + 1) + grow] = rstart;
  if (cb == NCB - 1 && t == 0) starts[dir * (NROW + 1) + NROW] = segEnd;
  cnt[t] = rstart;
  __syncthreads();
  for (uint32_t e = segStart + t; e < segEnd; e += 512) {
    const uint2 q = edgesA[e];
    const uint32_t pos = atomicAdd(&cnt[(q.x >> 19) & 511u], 1u);
    edgesB[pos] = q;
  }
}

// ---------------- fp32 -> fp8 table convert ----------------
__global__ __launch_bounds__(256) void fp8_convert(
    const float* __restrict__ src, u8* __restrict__ dst, int n4) {
  int i = blockIdx.x * 256 + threadIdx.x;
  if (i >= n4) return;
  float4 v = ((const float4*)src)[i];
  uint32_t o = (uint32_t)f2fp8(v.x) | ((uint32_t)f2fp8(v.y) << 8) |
               ((uint32_t)f2fp8(v.z) << 16) | ((uint32_t)f2fp8(v.w) << 24);
  ((uint32_t*)dst)[i] = o;
}

// Wt16[w][d][k] = bf16(W[w][k][d])  (pre-transposed for MFMA B-operand)
__global__ __launch_bounds__(256) void w16_prep(WPtrs wp, u16* __restrict__ Wt16) {
  int i = blockIdx.x * 256 + threadIdx.x;
  if (i >= 8 * 4096) return;
  int w = i >> 12, kd = i & 4095, k = kd >> 6, d = kd & 63;
  Wt16[w * 4096 + d * 64 + k] = f2bf(wp.W[w][k * 64 + d]);
}

// ---------------- fused spmm (wave/row, scalarized, fp8, both dirs) ----------------
__global__ __launch_bounds__(256) void spmm_row(
    const uint2* __restrict__ edges, const uint32_t* __restrict__ startsAbs,
    SpmmArgs a, int layer) {
  const int dir = blockIdx.y;
  const int row = rfl(blockIdx.x * 4 + (threadIdx.x >> 6));
  const int lane = threadIdx.x & 63;
  if (row >= NROW) return;
  const uint32_t* starts = startsAbs + dir * (NROW + 1);
  const u8* __restrict__ Einf = a.Einf[dir];
  const uint32_t s0 = rflu(starts[row]);
  const uint32_t s1 = rflu(starts[row + 1]);
  const uint32_t kbit = 1u << (17 + layer);
  float z = 0.f, zd = 0.f;
  uint32_t e = s0;
  for (; e + 8 <= s1; e += 8) {  // 8-deep unroll for gather MLP
    uint32_t p[8], wv[8], b[8];
#pragma unroll
    for (int k = 0; k < 8; ++k) {
      p[k] = rflu(edges[e + k].x);
      wv[k] = rflu(edges[e + k].y);
    }
#pragma unroll
    for (int k = 0; k < 8; ++k)
      b[k] = Einf[(size_t)(p[k] & 0x1FFFFu) * 64 + lane];
#pragma unroll
    for (int k = 0; k < 8; ++k) {
      const float x = fp8dec(b[k]);
      const float v = __uint_as_float(wv[k]);
      z += v * x;
      zd += ((p[k] & kbit) ? v : 0.f) * x;
    }
  }
  for (; e + 4 <= s1; e += 4) {
    const uint32_t p0 = rflu(edges[e].x),     w0 = rflu(edges[e].y);
    const uint32_t p1 = rflu(edges[e + 1].x), w1 = rflu(edges[e + 1].y);
    const uint32_t p2 = rflu(edges[e + 2].x), w2 = rflu(edges[e + 2].y);
    const uint32_t p3 = rflu(edges[e + 3].x), w3 = rflu(edges[e + 3].y);
    const uint32_t b0 = Einf[(size_t)(p0 & 0x1FFFFu) * 64 + lane];
    const uint32_t b1 = Einf[(size_t)(p1 & 0x1FFFFu) * 64 + lane];
    const uint32_t b2 = Einf[(size_t)(p2 & 0x1FFFFu) * 64 + lane];
    const uint32_t b3 = Einf[(size_t)(p3 & 0x1FFFFu) * 64 + lane];
    const float x0 = fp8dec(b0), x1 = fp8dec(b1);
    const float x2 = fp8dec(b2), x3 = fp8dec(b3);
    const float v0 = __uint_as_float(w0), v1 = __uint_as_float(w1);
    const float v2 = __uint_as_float(w2), v3 = __uint_as_float(w3);
    const float d0 = (p0 & kbit) ? v0 : 0.f;
    const float d1 = (p1 & kbit) ? v1 : 0.f;
    const float d2 = (p2 & kbit) ? v2 : 0.f;
    const float d3 = (p3 & kbit) ? v3 : 0.f;
    z += v0 * x0; zd += d0 * x0;
    z += v1 * x1; zd += d1 * x1;
    z += v2 * x2; zd += d2 * x2;
    z += v3 * x3; zd += d3 * x3;
  }
  for (; e < s1; ++e) {
    const uint32_t p = rflu(edges[e].x), wv = rflu(edges[e].y);
    const float x = fp8dec(Einf[(size_t)(p & 0x1FFFFu) * 64 + lane]);
    const float v = __uint_as_float(wv);
    z += v * x;
    zd += ((p & kbit) ? v : 0.f) * x;
  }
  z = leaky(z);
  zd = leaky(zd * (1.0f / 0.9f));
  // noise-augmented view
  const float u = tf_uniform(a.nk[dir][0], a.nk[dir][1],
                             (uint32_t)row * 64u + (uint32_t)lane);
  float ss = u * u;
#pragma unroll
  for (int off = 1; off < 64; off <<= 1) ss += __shfl_xor(ss, off);
  const float nrm = fmaxf(sqrtf(ss), 1e-12f);
  const float sg = (z > 0.f) ? 1.f : (z < 0.f ? -1.f : 0.f);
  z += sg * (u / nrm) * 0.1f;
  const size_t j = (size_t)row * 64 + lane;
  a.Z[dir][j] = f2bf(z);
  a.Zd[dir][j] = f2bf(zd);
  if (a.Enext[dir]) {  // layer 0 only
    const float en = z + zd + a.Eprev[dir][j];
    a.Enext[dir][j] = en;
    a.Enf8[dir][j] = f2fp8(en);
  }
}

// ---------------- dual-dir SVD middle matrix (fp8 E input, block-reduced) --------
// M[q][d] = 2^112 * sum_i T[q][i] * fp8dec(E[i][d])
__global__ __launch_bounds__(256) void svd_reduce2(
    const float* __restrict__ T0, const u8* __restrict__ E0f,
    const float* __restrict__ T1, const u8* __restrict__ E1f,
    float* __restrict__ Mu, float* __restrict__ Mi) {
  const int dir = blockIdx.y;
  const float* __restrict__ T = dir ? T1 : T0;
  const u8* __restrict__ E = dir ? E1f : E0f;
  float* __restrict__ M = dir ? Mi : Mu;
  const int lane = threadIdx.x & 63;
  const int wl = threadIdx.x >> 6;
  const int gw = rfl(blockIdx.x * 4 + wl);
  float a0 = 0.f, a1 = 0.f, a2 = 0.f, a3 = 0.f, a4 = 0.f;
  for (int i = gw; i < NROW; i += 4096) {
    const float x = fp8dec(E[(size_t)i * 64 + lane]);
    a0 += T[i] * x;
    a1 += T[NROW + i] * x;
    a2 += T[2 * NROW + i] * x;
    a3 += T[3 * NROW + i] * x;
    a4 += T[4 * NROW + i] * x;
  }
  __shared__ float red[4][5][64];
  red[wl][0][lane] = a0; red[wl][1][lane] = a1; red[wl][2][lane] = a2;
  red[wl][3][lane] = a3; red[wl][4][lane] = a4;
  __syncthreads();
  for (int o = threadIdx.x; o < 320; o += 256) {
    const int q = o >> 6, d = o & 63;
    const float s = red[0][q][d] + red[1][q][d] + red[2][q][d] + red[3][q][d];
    atomicAdd(&M[o], s * 0x1p112f);
  }
}

// gather batch rows & L2-normalize -> bf16; blockIdx.y selects {Z, Zd, G}
__global__ __launch_bounds__(256) void gather_norm(
    const int* __restrict__ ids, const u16* __restrict__ Z,
    const u16* __restrict__ Zd, const float* __restrict__ mul_s,
    const float* __restrict__ M, u16* __restrict__ oZ,
    u16* __restrict__ oZd, u16* __restrict__ oG) {
  long long t = (long long)blockIdx.x * blockDim.x + threadIdx.x;
  int b = (int)(t >> 6);
  int d = (int)(t & 63);
  if (b >= C_B) return;
  int id = rfl(ids[b]);
  float v;
  u16* out;
  if (blockIdx.y == 0) { v = bf2f(Z[(size_t)id * 64 + d]); out = oZ; }
  else if (blockIdx.y == 1) { v = bf2f(Zd[(size_t)id * 64 + d]); out = oZd; }
  else {
    float s = 0.f;
#pragma unroll
    for (int q = 0; q < 5; ++q) s += mul_s[(size_t)id * 5 + q] * M[q * 64 + d];
    v = leaky(s);
    out = oG;
  }
  float ss = v * v;
#pragma unroll
  for (int off = 1; off < 64; off <<= 1) ss += __shfl_xor(ss, off);
  float nrm = fmaxf(sqrtf(ss), 1e-12f);
  out[(size_t)b * 64 + d] = f2bf(v / nrm);
}

// ---------------- MFMA hyper (LDS-free): hy = (X @ W) * log2e/TEMP ----------------
__global__ __launch_bounds__(256) void hyper_mfma(
    const u16* __restrict__ nb, const u16* __restrict__ Wt16,
    u16* __restrict__ hy) {
  const int call = blockIdx.y;
  const int b0 = blockIdx.x * 64;
  const int lane = threadIdx.x & 63, wid = threadIdx.x >> 6;
  const u16* X = nb + (size_t)c_hsrc[call] * C_B * 64;
  const u16* Wt = Wt16 + (size_t)c_wsel[call] * 4096;
  const int am = (wid << 4) + (lane & 15);
  const int ke = ((lane >> 4) << 3);  // fragment k-offset (elements)
  short8 af[2];
#pragma unroll
  for (int ks = 0; ks < 2; ++ks)
    af[ks] = *(const short8*)&X[(size_t)(b0 + am) * 64 + ks * 32 + ke];
  const int ob = b0 + (wid << 4) + ((lane >> 4) << 2);
#pragma unroll
  for (int n = 0; n < 4; ++n) {
    const int bn = (n << 4) + (lane & 15);
    f32x4 acc = {0.f, 0.f, 0.f, 0.f};
#pragma unroll
    for (int ks = 0; ks < 2; ++ks) {
      short8 bf = *(const short8*)&Wt[(size_t)bn * 64 + ks * 32 + ke];
      acc = __builtin_amdgcn_mfma_f32_16x16x32_bf16(af[ks], bf, acc, 0, 0, 0);
    }
    const int d = (n << 4) + (lane & 15);
#pragma unroll
    for (int j = 0; j < 4; ++j)
      hy[(size_t)call * C_B * 64 + (size_t)(ob + j) * 64 + d] =
          f2bf(acc[j] * 7.2134752f);  // fold log2(e)/TEMP into H
  }
}

// ---------------- MFMA info_nce partials: 128 g-rows x 16 H-tiles per block ----
// grid: (32 g-tiles, 4 jt-chunks, 16 calls); G fragments loaded direct from global
__global__ __launch_bounds__(256) void nce_partial(
    const u16* __restrict__ nb, const u16* __restrict__ hy,
    float* __restrict__ rsbuf, float* __restrict__ psbuf) {
  const int call = blockIdx.z;
  const int jc = blockIdx.y;
  const u16* G = nb + (size_t)c_gsel[call] * C_B * 64;
  const u16* H = hy + (size_t)call * C_B * 64;
  const int br = blockIdx.x * 128;
  const int jt0 = jc * 16;
  __shared__ u16 Hs[2][64 * 64];
  const int tid = threadIdx.x, lane = tid & 63, wid = tid >> 6;
  const int ke = ((lane >> 4) << 3);
  short8 bfG[2][2];
#pragma unroll
  for (int s = 0; s < 2; ++s)
#pragma unroll
    for (int ks = 0; ks < 2; ++ks) {
      const int gc = (wid << 5) + (s << 4) + (lane & 15);
      bfG[s][ks] = *(const short8*)&G[(size_t)(br + gc) * 64 + ks * 32 + ke];
    }
  const int r = tid >> 2, seg = tid & 3;
  const int base = r * 128 + seg * 32, sw = (r & 7) << 4;
  {
    const uint4* src = (const uint4*)&H[(size_t)(jt0 * 64 + r) * 64 + seg * 16];
    uint4 a = src[0], b = src[1];
    *(uint4*)((char*)Hs[0] + (base ^ sw)) = a;
    *(uint4*)((char*)Hs[0] + ((base + 16) ^ sw)) = b;
  }
  float rs[2] = {0.f, 0.f}, ps[2] = {0.f, 0.f};
  const int jt_diag = (blockIdx.x << 1) + (wid >> 1);
  const int hsd0 = (wid & 1) << 1;
  int cur = 0;
  for (int jt = jt0; jt < jt0 + 16; ++jt) {
    __syncthreads();  // Hs[cur] ready
    uint4 na, nb_;
    if (jt + 1 < jt0 + 16) {  // prefetch next H tile
      const uint4* src = (const uint4*)&H[(size_t)((jt + 1) * 64 + r) * 64 + seg * 16];
      na = src[0]; nb_ = src[1];
    }
    const bool dj = (jt == jt_diag);
    const char* Hb = (const char*)(Hs[cur]);
#pragma unroll
    for (int hs = 0; hs < 4; ++hs) {
      const int hr = (hs << 4) + (lane & 15);
      const int offA0 = (hr * 128 + ((lane >> 4) << 4)) ^ ((hr & 7) << 4);
      const int offA1 = (hr * 128 + 64 + ((lane >> 4) << 4)) ^ ((hr & 7) << 4);
      const short8 af0 = *(const short8*)(Hb + offA0);
      const short8 af1 = *(const short8*)(Hb + offA1);
      f32x4 acc0 = {0.f, 0.f, 0.f, 0.f}, acc1 = {0.f, 0.f, 0.f, 0.f};
      __builtin_amdgcn_s_setprio(1);
      acc0 = __builtin_amdgcn_mfma_f32_16x16x32_bf16(af0, bfG[0][0], acc0, 0, 0, 0);
      acc0 = __builtin_amdgcn_mfma_f32_16x16x32_bf16(af1, bfG[0][1], acc0, 0, 0, 0);
      acc1 = __builtin_amdgcn_mfma_f32_16x16x32_bf16(af0, bfG[1][0], acc1, 0, 0, 0);
      acc1 = __builtin_amdgcn_mfma_f32_16x16x32_bf16(af1, bfG[1][1], acc1, 0, 0, 0);
      __builtin_amdgcn_s_setprio(0);
      float e0[4], e1[4];
#pragma unroll
      for (int j = 0; j < 4; ++j) {
        e0[j] = fast_exp2(acc0[j]);  // H pre-scaled by log2e/TEMP
        e1[j] = fast_exp2(acc1[j]);
      }
      rs[0] += (e0[0] + e0[1]) + (e0[2] + e0[3]);
      rs[1] += (e1[0] + e1[1]) + (e1[2] + e1[3]);
      if (dj) {
        const int jm = (lane & 15) - ((lane >> 4) << 2);
        if (hs == hsd0) {
#pragma unroll
          for (int j = 0; j < 4; ++j)
            if (jm == j) ps[0] = e0[j];
        }
        if (hs == hsd0 + 1) {
#pragma unroll
          for (int j = 0; j < 4; ++j)
            if (jm == j) ps[1] = e1[j];
        }
      }
    }
    if (jt + 1 < jt0 + 16) {
      *(uint4*)((char*)Hs[cur ^ 1] + (base ^ sw)) = na;
      *(uint4*)((char*)Hs[cur ^ 1] + ((base + 16) ^ sw)) = nb_;
    }
    cur ^= 1;
  }
#pragma unroll
  for (int s = 0; s < 2; ++s) {
    rs[s] += __shfl_xor(rs[s], 16); rs[s] += __shfl_xor(rs[s], 32);
    ps[s] += __shfl_xor(ps[s], 16); ps[s] += __shfl_xor(ps[s], 32);
  }
  if ((lane >> 4) == 0) {
    const bool own_diag = ((jt_diag >> 4) == jc);  // wave-uniform
#pragma unroll
    for (int s = 0; s < 2; ++s) {
      const int gg = br + (wid << 5) + (s << 4) + (lane & 15);
      atomicAdd(&rsbuf[(size_t)call * C_B + gg], rs[s]);
      if (own_diag) psbuf[(size_t)call * C_B + gg] = ps[s];
    }
  }
}

// finalize: v = -log(ps/(rs+eps)+eps), mask, reduce to slots
__global__ __launch_bounds__(256) void nce_final(
    const float* __restrict__ rsbuf, const float* __restrict__ psbuf,
    float* __restrict__ slots, NceKeys nk) {
  const int call = blockIdx.y;
  const int g = blockIdx.x * 256 + threadIdx.x;
  const float rs = rsbuf[(size_t)call * C_B + g];
  const float ps = psbuf[(size_t)call * C_B + g];
  const float v = -__logf(ps / (rs + 1e-8f) + 1e-8f);
  const float u = tf_uniform(nk.k0[call], nk.k1[call], (uint32_t)g);
  float c = (u > 0.5f) ? v : 0.f;
#pragma unroll
  for (int off = 1; off < 64; off <<= 1) c += __shfl_xor(c, off);
  __shared__ float wsum[4];
  if ((threadIdx.x & 63) == 0) wsum[threadIdx.x >> 6] = c;
  __syncthreads();
  if (threadIdx.x == 0)
    atomicAdd(&slots[c_slot[call]], wsum[0] + wsum[1] + wsum[2] + wsum[3]);
}

// E_sum = E0 + 2*E1 + Z2 + Zd2  (E2 never materialized; Z in bf16)
__global__ __launch_bounds__(256) void loss_r_kernel(
    const float* __restrict__ E0u, const float* __restrict__ Eu1,
    const u16* __restrict__ Zu, const u16* __restrict__ Zdu,
    const float* __restrict__ E0i, const float* __restrict__ Ei1,
    const u16* __restrict__ Zi, const u16* __restrict__ Zdi,
    const int* __restrict__ uids, const int* __restrict__ pos,
    const int* __restrict__ neg, float* __restrict__ slots) {
  long long t = (long long)blockIdx.x * blockDim.x + threadIdx.x;
  int b = (int)(t >> 6);
  int d = (int)(t & 63);
  if (b >= C_B) return;
  size_t ju = (size_t)rfl(uids[b]) * 64 + d;
  float u = E0u[ju] + 2.f * Eu1[ju] + bf2f(Zu[ju]) + bf2f(Zdu[ju]);
  float bpr = 0.f, pmin = 3.4e38f, nmax = -3.4e38f;
  for (int p = 0; p < C_P; ++p) {
    size_t jp = (size_t)rfl(pos[b * C_P + p]) * 64 + d;
    size_t jn = (size_t)rfl(neg[b * C_P + p]) * 64 + d;
    float pe = E0i[jp] + 2.f * Ei1[jp] + bf2f(Zi[jp]) + bf2f(Zdi[jp]);
    float ne = E0i[jn] + 2.f * Ei1[jn] + bf2f(Zi[jn]) + bf2f(Zdi[jn]);
    float psc = u * pe, nsc = u * ne;
#pragma unroll
    for (int off = 1; off < 64; off <<= 1) {
      psc += __shfl_xor(psc, off);
      nsc += __shfl_xor(nsc, off);
    }
    pmin = fminf(pmin, psc);
    nmax = fmaxf(nmax, nsc);
    bpr += fmaxf(1.f - psc + nsc, 0.f);
  }
  if (d == 0) {
    float hd = (nmax - pmin > 0.005f) ? 10.f * (nmax - pmin) : 0.f;
    atomicAdd(&slots[5], bpr + hd);
  }
}

__global__ void final_kernel(const float* __restrict__ slots, float* __restrict__ out) {
  if (threadIdx.x == 0 && blockIdx.x == 0) {
    float n = slots[0], dl = slots[1], nn = slots[2], dd = slots[3], nd = slots[4];
    float lr = slots[5] / (float)C_B;
    out[0] = lr + 0.2f * (n + dl) + 0.2f * (nn + dd + nd);
    out[1] = lr;
    out[2] = dl;
    out[3] = n;
  }
}

// ---------------- host ----------------
extern "C" void kernel_launch(void* const* d_in, const int* in_sizes, int n_in,
                              void* d_out, int out_size, void* d_ws, size_t ws_size,
                              hipStream_t stream) {
  (void)in_sizes; (void)n_in; (void)out_size;
  const float* E_u_0   = (const float*)d_in[0];
  const float* E_i_0   = (const float*)d_in[1];
  const float* adjvals = (const float*)d_in[2];
  const float* u_mul_s = (const float*)d_in[3];
  const float* v_mul_s = (const float*)d_in[4];
  const float* ut      = (const float*)d_in[5];
  const float* vt      = (const float*)d_in[6];
  const float* W_nn    = (const float*)d_in[7];
  const float* W_dd    = (const float*)d_in[8];
  const float* W_ng    = (const float*)d_in[9];
  const float* W_dg    = (const float*)d_in[10];
  const float* W_nd    = (const float*)d_in[11];
  const int* adj_rows  = (const int*)d_in[12];
  const int* adj_cols  = (const int*)d_in[13];
  const int* uids      = (const int*)d_in[14];
  const int* iids      = (const int*)d_in[15];
  const int* pos       = (const int*)d_in[16];
  const int* neg       = (const int*)d_in[17];
  float* out = (float*)d_out;

  const size_t NU64 = (size_t)C_NU * 64;
  const size_t NI64 = (size_t)C_NI * 64;
  const size_t B64  = (size_t)C_B * 64;

  float* w = (float*)d_ws;
  float* Eu1 = w; w += NU64;
  float* Ei1 = w; w += NI64;
  u16* Zu  = (u16*)w;            // 4 contiguous bf16 Z buffers; edgesA aliases
  u16* Zdu = Zu + NU64;
  u16* Zi  = Zdu + NU64;
  u16* Zdi = Zi + NI64;
  w += 2 * NU64;                 // 4 * NU64 u16 = 2 * NU64 floats
  float* Mu = w; w += 512;
  float* Mi = w; w += 512;
  u16* normbuf16 = (u16*)w; w += 6 * B64;     // 12 bf16 buffers of B64
  float* slots = w; w += 16;
  uint2* edgesB = (uint2*)w; w += 4 * C_NE;   // 32 MB final CSR (both dirs)
  u16* hyper16 = (u16*)edgesB;                // alias: edgesB dead before hyper
  u16* Wt16 = (u16*)w; w += 16384;
  uint32_t* cntA = (uint32_t*)w; w += NCB * NCHK * 2;
  uint32_t* offs = (uint32_t*)w; w += NCB * NCHK * 2;
  uint32_t* bsumA = (uint32_t*)w; w += NCB;
  uint32_t* boffA = (uint32_t*)w; w += NCB;
  uint32_t* startsAbs = (uint32_t*)w; w += 2 * (NROW + 1);
  u8* Eu0f = (u8*)w; w += NU64 / 4;           // fp8 gather tables
  u8* Ei0f = (u8*)w; w += NI64 / 4;
  u8* Eu1f = (u8*)w; w += NU64 / 4;
  u8* Ei1f = (u8*)w; w += NI64 / 4;           // own storage (no alias)
  float* rsbuf = w; w += 16 * C_B;            // nce partial denominators
  float* psbuf = w; w += 16 * C_B;            // nce diag numerators
  uint2* edgesA = (uint2*)Zu;                 // 32 MB coarse buffer (< Zu..Zi)
  if ((size_t)((char*)w - (char*)d_ws) > ws_size) return;

  // ---- host-side JAX key derivation (partitionable threefry) ----
  auto ksplit = [](uint32_t a, uint32_t b, uint32_t idx, uint32_t& o0, uint32_t& o1) {
    uint32_t x0 = 0u, x1 = idx;
    tf2x32(a, b, x0, x1);
    o0 = x0; o1 = x1;
  };
  uint32_t rk0 = 0u, rk1 = 42u;
  uint32_t lk[2][4][2];
  for (int l = 0; l < 2; ++l) {
    uint32_t n0, n1;
    ksplit(rk0, rk1, 0u, n0, n1);
    for (int i = 0; i < 4; ++i) ksplit(rk0, rk1, (uint32_t)(i + 1), lk[l][i][0], lk[l][i][1]);
    rk0 = n0; rk1 = n1;
  }
  NceKeys nk;
  {
    uint32_t mk0 = 0u, mk1 = 7u;
    for (int i = 0; i < 16; ++i) {
      uint32_t n0, n1;
      ksplit(mk0, mk1, 0u, n0, n1);
      ksplit(mk0, mk1, 1u, nk.k0[i], nk.k1[i]);
      mk0 = n0; mk1 = n1;
    }
  }
  DropKeys dk;
  dk.a[0] = lk[0][0][0]; dk.a[1] = lk[0][0][1];
  dk.a[2] = lk[1][0][0]; dk.a[3] = lk[1][0][1];
  dk.a[4] = lk[0][1][0]; dk.a[5] = lk[0][1][1];
  dk.a[6] = lk[1][1][0]; dk.a[7] = lk[1][1][1];
  WPtrs wp;
  wp.W[0] = W_ng; wp.W[1] = W_ng + 4096;
  wp.W[2] = W_nn;
  wp.W[3] = W_dg; wp.W[4] = W_dg + 4096;
  wp.W[5] = W_dd;
  wp.W[6] = W_nd; wp.W[7] = W_nd + 4096;

  // ---- sort + preps ----
  hipMemsetAsync(slots, 0, 16 * 4, stream);
  hipMemsetAsync(rsbuf, 0, 16 * C_B * 4, stream);
  passA_hist<<<dim3(NCHK, 2), 256, 0, stream>>>(adj_rows, adj_cols, cntA);
  scanA1<<<NCB, 512, 0, stream>>>(cntA, offs, bsumA);
  scanA2<<<1, 256, 0, stream>>>(bsumA, boffA);
  scanA3<<<NCB, 512, 0, stream>>>(offs, boffA);
  passA_scatter<<<dim3(NCHK, 2), 256, 0, stream>>>(
      adj_rows, adj_cols, adjvals, offs, edgesA, dk);
  passB_kernel<<<dim3(NCB, 2), 512, 0, stream>>>(edgesA, offs, edgesB, startsAbs);
  fp8_convert<<<(int)(NU64 / 4 + 255) / 256, 256, 0, stream>>>(E_u_0, Eu0f, (int)(NU64 / 4));
  fp8_convert<<<(int)(NI64 / 4 + 255) / 256, 256, 0, stream>>>(E_i_0, Ei0f, (int)(NI64 / 4));
  w16_prep<<<(8 * 4096 + 255) / 256, 256, 0, stream>>>(wp, Wt16);

  const int gb = (int)(B64 / 256);  // 1024
  const int sb = (NROW + 3) / 4;    // 25000 blocks, 4 waves each

  for (int l = 0; l < 2; ++l) {
    hipMemsetAsync(Mu, 0, 1024 * 4, stream);  // Mu+Mi contiguous
    svd_reduce2<<<dim3(1024, 2), 256, 0, stream>>>(
        vt, (l == 0) ? Ei0f : Ei1f, ut, (l == 0) ? Eu0f : Eu1f, Mu, Mi);
    SpmmArgs sa;
    sa.Einf[0] = (l == 0) ? Ei0f : Ei1f;  // dir0 gathers items
    sa.Einf[1] = (l == 0) ? Eu0f : Eu1f;  // dir1 gathers users
    sa.Eprev[0] = (l == 0) ? E_u_0 : nullptr;
    sa.Eprev[1] = (l == 0) ? E_i_0 : nullptr;
    sa.Enext[0] = (l == 0) ? Eu1 : nullptr;
    sa.Enext[1] = (l == 0) ? Ei1 : nullptr;
    sa.Enf8[0] = (l == 0) ? Eu1f : nullptr;
    sa.Enf8[1] = (l == 0) ? Ei1f : nullptr;
    sa.Z[0] = Zu; sa.Zd[0] = Zdu;
    sa.Z[1] = Zi; sa.Zd[1] = Zdi;
    sa.nk[0][0] = lk[l][2][0]; sa.nk[0][1] = lk[l][2][1];
    sa.nk[1][0] = lk[l][3][0]; sa.nk[1][1] = lk[l][3][1];
    spmm_row<<<dim3(sb, 2), 256, 0, stream>>>(edgesB, startsAbs, sa, l);
    gather_norm<<<dim3(gb, 3), 256, 0, stream>>>(
        uids, Zu, Zdu, u_mul_s, Mu,
        normbuf16 + (size_t)(0 + l) * B64, normbuf16 + (size_t)(4 + l) * B64,
        normbuf16 + (size_t)(8 + l) * B64);
    gather_norm<<<dim3(gb, 3), 256, 0, stream>>>(
        iids, Zi, Zdi, v_mul_s, Mi,
        normbuf16 + (size_t)(2 + l) * B64, normbuf16 + (size_t)(6 + l) * B64,
        normbuf16 + (size_t)(10 + l) * B64);
  }

  hyper_mfma<<<dim3(C_B / 64, 16), 256, 0, stream>>>(normbuf16, Wt16, hyper16);
  nce_partial<<<dim3(C_B / 128, 4, 16), 256, 0, stream>>>(normbuf16, hyper16,
                                                          rsbuf, psbuf);
  nce_final<<<dim3(C_B / 256, 16), 256, 0, stream>>>(rsbuf, psbuf, slots, nk);
  loss_r_kernel<<<gb, 256, 0, stream>>>(E_u_0, Eu1, Zu, Zdu, E_i_0, Ei1, Zi, Zdi,
                                        uids, pos, neg, slots);
  final_kernel<<<1, 1, 0, stream>>>(slots, out);
}